// Round 4
// baseline (377.496 us; speedup 1.0000x reference)
//
#include <hip/hip_runtime.h>
#include <hip/hip_bf16.h>

#define BB 16
#define NN 1024
#define FF 128
#define HH 192
#define NROWS (BB*NN)
#define MAXC 128
#define EPSV 1e-5f
#define NTHR 512

// ---------------- workspace layout (float units) ----------------
constexpr size_t OFF_H0  = 0;                                 // [NROWS*HH] bf16 (h, post-relu)
constexpr size_t OFF_ZB  = OFF_H0 + (size_t)NROWS*HH/2;       // [NROWS*HH] bf16 (Z')
constexpr size_t OFF_DIS = OFF_ZB + (size_t)NROWS*HH/2;       // [NROWS] f32
constexpr size_t OFF_G   = OFF_DIS + NROWS;                   // [BB*HH] pool sums (atomics)
constexpr size_t OFF_SH  = OFF_G + BB*HH;                     // 3 stages x 8 buckets x 512
constexpr size_t SH_SIZE = 3*8*512;
constexpr size_t OFF_FLG = OFF_SH + SH_SIZE;                  // [3*16] int flags + pad
constexpr size_t FLG_SZ  = 64;
constexpr size_t ZERO_SZ = BB*HH + SH_SIZE + FLG_SZ;          // zeroed in K1 (15424)
constexpr size_t OFF_XB  = OFF_FLG + FLG_SZ;                  // x-stat buckets [64][256]
constexpr size_t OFF_CNT = OFF_XB + 64*256;                   // [NROWS] int32
constexpr size_t OFF_COLS= OFF_CNT + NROWS;                   // [NROWS*MAXC] u16

typedef __attribute__((ext_vector_type(8))) short short8;
typedef __attribute__((ext_vector_type(4))) float f32x4;
typedef __attribute__((ext_vector_type(4))) unsigned int u32x4;
typedef __attribute__((ext_vector_type(2))) unsigned int u32x2;

static __device__ __forceinline__ float ldin(const void* p, size_t i, int isf) {
    return isf ? ((const float*)p)[i]
               : __bfloat162float(((const __hip_bfloat16*)p)[i]);
}
static __device__ __forceinline__ float blo(unsigned int u) {
    union { unsigned int x; float f; } v; v.x = u << 16; return v.f;
}
static __device__ __forceinline__ float bhi(unsigned int u) {
    union { unsigned int x; float f; } v; v.x = u & 0xFFFF0000u; return v.f;
}
static __device__ __forceinline__ unsigned int packbf(float a, float b) {
    union { unsigned int u; __hip_bfloat16 h[2]; } p;
    p.h[0] = __float2bfloat16(a); p.h[1] = __float2bfloat16(b);
    return p.u;
}
static __device__ __forceinline__ unsigned short bf16bits(float a) {
    union { unsigned short u; __hip_bfloat16 h; } p;
    p.h = __float2bfloat16(a); return p.u;
}

// dtype self-detection: adj elements are exactly {0,1}; f32 words never have
// low16 == 0x3F80, packed-bf16 1.0 entries do (~20 hits in first 1024 words).
template<int T>
static __device__ __forceinline__ int detect_isf(const unsigned int* __restrict__ adjw,
                                                 int tid, int* sh_flag) {
    if (tid == 0) *sh_flag = 0;
    __syncthreads();
    int hit = 0;
    for (int k = tid; k < 1024; k += T)
        if ((adjw[k] & 0xFFFFu) == 0x3F80u) hit = 1;
    if (hit) *sh_flag = 1;
    __syncthreads();
    return (*sh_flag == 0) ? 1 : 0;
}

// ================= K1: zero atomic regions + x-stats ========================
// grid 96: all blocks zero; bid<64 do one x-stat task (256 rows x 128 feats).
// LDS: XS f32[1024]
__global__ __launch_bounds__(NTHR, 8) void k_prep(const void* __restrict__ adj,
                                                  const void* __restrict__ x, float* ws) {
    __shared__ __align__(16) float XS[1024];
    __shared__ int sflag;
    int tid = threadIdx.x, bid = blockIdx.x;
    const int isf = detect_isf<NTHR>((const unsigned int*)adj, tid, &sflag);
    for (size_t i = (size_t)bid*NTHR + tid; i < ZERO_SZ; i += (size_t)96*NTHR)
        ws[OFF_G + i] = 0.f;
    if (bid < 64) {
        int f = tid & 127, part = tid >> 7;           // 4 parts x 64 rows
        int t = bid;
        int r0 = t*256 + part*64;
        float s = 0.f, q = 0.f;
        for (int r = 0; r < 64; ++r) {
            float v = ldin(x, (size_t)(r0 + r)*FF + f, isf);
            s += v; q += v*v;
        }
        XS[part*128 + f] = s; XS[512 + part*128 + f] = q;
        __syncthreads();
        if (part == 0) {
            float ss = XS[f] + XS[128+f] + XS[256+f] + XS[384+f];
            float qq = XS[512+f] + XS[640+f] + XS[768+f] + XS[896+f];
            ws[OFF_XB + (size_t)t*256 + f] = ss;
            ws[OFF_XB + (size_t)t*256 + 128 + f] = qq;
        }
    }
}

// ================= shared GEMM core =========================================
// One 32-row x 192-col tile, 8 waves (2 row x 4 col), 3 frags/wave.
// MODE 0 (K=FF): A = x (f32 or bf16), epilogue H0 scatter + stage0 stats.
// MODE 1 (K=HH): A = H0 bf16, epilogue Z (LDS transpose -> coalesced
//                agent-scope u32 stores) + per-batch flag release.
// LDS: WB bf16[192*K] @0 ; AF @WB+0 ; CF @+768 ; BSUM @+1536 ; SH2 @+2304
template<int K, int MODE>
static __device__ void gemm_core(char* SM_, int tid, int isf, int t,
                                 const void* Asrc, const void* Wsrc,
                                 const void* gsrc, const void* bsrc,
                                 int layer, float* ws) {
    constexpr int WBYTES = 192*K*2;
    __hip_bfloat16* WB = (__hip_bfloat16*)SM_;
    float* AF   = (float*)(SM_ + WBYTES);
    float* CF   = (float*)(SM_ + WBYTES + 768);
    float* BSUM = (float*)(SM_ + WBYTES + 1536);
    float* SH2  = (float*)(SM_ + WBYTES + 2304);      // [384] MODE0 only
    int lane = tid & 63, w = tid >> 6;
    int wr = w & 1, wc = w >> 1;                      // 2 x 4 waves
    int m = lane & 15, quad = lane >> 4;
    // ---- BN scale/shift (redundant per block, L2-hot) ----
    if (MODE == 0) {
        if (tid < FF) {
            float s = 0.f, q = 0.f;
            for (int b = 0; b < 64; ++b) {
                s += ws[OFF_XB + (size_t)b*256 + tid];
                q += ws[OFF_XB + (size_t)b*256 + 128 + tid];
            }
            float mean = s*(1.f/NROWS), var = q*(1.f/NROWS) - mean*mean;
            float a = ldin(gsrc, tid, isf) * rsqrtf(var + EPSV);
            AF[tid] = a;
            CF[tid] = ldin(bsrc, tid, isf) - mean*a;
        }
    } else {
        if (tid < HH) {
            const float* st = ws + OFF_SH + (size_t)layer*4096;
            float s = 0.f, q = 0.f;
            #pragma unroll
            for (int b = 0; b < 8; ++b) {
                s += st[b*512 + tid];
                q += st[b*512 + 256 + tid];
            }
            float mean = s*(1.f/NROWS), var = q*(1.f/NROWS) - mean*mean;
            float a = ldin(gsrc, (size_t)layer*HH + tid, isf) * rsqrtf(var + EPSV);
            AF[tid] = a;
            CF[tid] = ldin(bsrc, (size_t)layer*HH + tid, isf) - mean*a;
        }
    }
    if (tid < 192) BSUM[tid] = 0.f;
    __syncthreads();
    int batch = t & 15, seg = t >> 4;
    int row0 = batch*NN + seg*32;
    const size_t woff = (MODE == 1) ? (size_t)layer*HH*HH : 0;
    // ---- fold W' -> LDS: thread = (nl, 8 consecutive k); b128 store --------
    {
        constexpr int TASKS = 192*(K/8);
        for (int idx = tid; idx < TASKS; idx += NTHR) {
            int nl = idx % 192;
            int k0 = (idx / 192) * 8;
            float wv[8]; float pa = 0.f;
            #pragma unroll
            for (int kk = 0; kk < 8; ++kk) {
                wv[kk] = ldin(Wsrc, woff + (size_t)(k0+kk)*HH + nl, isf);
                pa += CF[k0+kk]*wv[kk];
            }
            union { short8 s8; __hip_bfloat16 h[8]; } u;
            #pragma unroll
            for (int kk = 0; kk < 8; ++kk) u.h[kk] = __float2bfloat16(AF[k0+kk]*wv[kk]);
            int boff = ((nl*K + k0) << 1) ^ ((nl & 7) << 4);
            *(short8*)((char*)WB + boff) = u.s8;
            atomicAdd(&BSUM[nl], pa);
        }
    }
    __syncthreads();
    // ---- MFMA ----
    int rowA = row0 + wr*16 + m;
    f32x4 acc[3];
    #pragma unroll
    for (int tt = 0; tt < 3; ++tt) acc[tt] = f32x4{0.f,0.f,0.f,0.f};
    #pragma unroll
    for (int kb = 0; kb < K/32; ++kb) {
        short8 a;
        if (MODE == 0 && isf) {
            const float* Ar = (const float*)Asrc + (size_t)rowA*K + kb*32 + quad*8;
            f32x4 v0 = *(const f32x4*)Ar, v1 = *(const f32x4*)(Ar + 4);
            union { short8 s8; __hip_bfloat16 h[8]; } u;
            #pragma unroll
            for (int e = 0; e < 4; ++e) {
                u.h[e]   = __float2bfloat16(v0[e]);
                u.h[e+4] = __float2bfloat16(v1[e]);
            }
            a = u.s8;
        } else {
            a = *(const short8*)((const __hip_bfloat16*)Asrc + (size_t)rowA*K + kb*32 + quad*8);
        }
        #pragma unroll
        for (int tt = 0; tt < 3; ++tt) {
            int nl = wc*48 + tt*16 + m;
            int boff = ((nl*K + kb*32 + quad*8) << 1) ^ ((nl & 7) << 4);
            short8 b = *(const short8*)((char*)WB + boff);
            acc[tt] = __builtin_amdgcn_mfma_f32_16x16x32_bf16(a, b, acc[tt], 0, 0, 0);
        }
    }
    // ---- epilogue ----
    if (MODE == 0) {
        if (tid < 384) SH2[tid] = 0.f;
        __syncthreads();
        __hip_bfloat16* H0 = (__hip_bfloat16*)(ws + OFF_H0);
        #pragma unroll
        for (int tt = 0; tt < 3; ++tt) {
            int nl = wc*48 + tt*16 + m;
            float s = 0.f, sq = 0.f;
            #pragma unroll
            for (int r = 0; r < 4; ++r) {
                int row = row0 + wr*16 + quad*4 + r;
                float o = fmaxf(acc[tt][r] + BSUM[nl], 0.f);
                H0[(size_t)row*HH + nl] = __float2bfloat16(o);
                s += o; sq += o*o;
            }
            atomicAdd(&SH2[nl], s);
            atomicAdd(&SH2[192 + nl], sq);
        }
        __syncthreads();
        float* st = ws + OFF_SH + (size_t)(t & 7)*512;
        if (tid < 192) {
            atomicAdd(&st[tid], SH2[tid]);
            atomicAdd(&st[256 + tid], SH2[192 + tid]);
        }
    } else {
        __syncthreads();                              // WB free -> reuse as ZT
        unsigned short* ZT = (unsigned short*)SM_;    // [32][192] bf16 bits
        const float* dis = ws + OFF_DIS;
        float sc[4];
        #pragma unroll
        for (int r = 0; r < 4; ++r) sc[r] = dis[row0 + wr*16 + quad*4 + r];
        #pragma unroll
        for (int tt = 0; tt < 3; ++tt) {
            int nl = wc*48 + tt*16 + m;
            #pragma unroll
            for (int r = 0; r < 4; ++r)
                ZT[(wr*16 + quad*4 + r)*192 + nl] =
                    bf16bits((acc[tt][r] + BSUM[nl])*sc[r]);
        }
        __syncthreads();
        // coalesced agent-scope stores (cross-XCD visible without L2 flush)
        unsigned int* Zg = (unsigned int*)(ws + OFF_ZB);
        const unsigned int* ZTu = (const unsigned int*)ZT;
        for (int i = tid; i < 32*96; i += NTHR) {
            int rr = i / 96, cc = i - rr*96;
            __hip_atomic_store(&Zg[(size_t)(row0 + rr)*96 + cc], ZTu[rr*96 + cc],
                               __ATOMIC_RELAXED, __HIP_MEMORY_SCOPE_AGENT);
        }
        asm volatile("s_waitcnt vmcnt(0)" ::: "memory");
        __syncthreads();
        if (tid == 0) {
            int* fl = (int*)(ws + OFF_FLG) + layer*16 + batch;
            __hip_atomic_fetch_add(fl, 1, __ATOMIC_RELAXED, __HIP_MEMORY_SCOPE_AGENT);
        }
    }
}

// ================= graph task (4 adj rows per task) =========================
// LDS: CNT4 int[4] @cb_off-16 ... pass explicit pointers.
static __device__ void graph_task(int p, int tid, int isf,
                                  int* CNT4, unsigned short* CB,
                                  const void* adj, float* ws) {
    int lane = tid & 127, quarter = tid >> 7;
    int row = p*4 + quarter;
    int i = row & (NN - 1);
    if (lane == 0) CNT4[quarter] = 0;
    __syncthreads();
    int j0 = lane*8;
    unsigned int bits[8];
    if (isf) {
        const unsigned int* ap = (const unsigned int*)adj + (size_t)row*NN + j0;
        u32x4 v0 = *(const u32x4*)ap;
        u32x4 v1 = *(const u32x4*)(ap + 4);
        bits[0]=v0[0]; bits[1]=v0[1]; bits[2]=v0[2]; bits[3]=v0[3];
        bits[4]=v1[0]; bits[5]=v1[1]; bits[6]=v1[2]; bits[7]=v1[3];
    } else {
        const unsigned short* ap = (const unsigned short*)adj + (size_t)row*NN + j0;
        u32x4 v = *(const u32x4*)ap;
        #pragma unroll
        for (int e = 0; e < 4; ++e) { bits[2*e] = v[e] & 0xFFFFu; bits[2*e+1] = v[e] >> 16; }
    }
    #pragma unroll
    for (int e = 0; e < 8; ++e) {
        int j = j0 + e;
        if ((bits[e] << 1) != 0u || j == i) {
            int p2 = atomicAdd(&CNT4[quarter], 1);
            if (p2 < MAXC) CB[quarter*MAXC + p2] = (unsigned short)j;
        }
    }
    __syncthreads();
    int c = CNT4[quarter];
    int cc = c > MAXC ? MAXC : c;
    if (lane == 0) {
        ((int*)(ws + OFF_CNT))[row] = cc;
        ws[OFF_DIS + row] = rsqrtf((float)c);         // deg >= 1 (self loop)
    }
    unsigned short* cols = (unsigned short*)(ws + OFF_COLS);
    for (int k = lane; k < cc; k += 128) cols[(size_t)row*MAXC + k] = CB[quarter*MAXC + k];
    __syncthreads();
}

// ================= K2: gemm0 (bid<512) + graph build (all, strided) =========
// LDS: WB 49152 ; AF/CF/BSUM/SH2 -> end 52992 ; CB u16[4][128] @52992 ;
//      CNT4 @54016 ; total 54032 -> 3 blocks/CU.
__global__ __launch_bounds__(NTHR, 6) void k_gg0(const void* __restrict__ adj,
        const void* __restrict__ x, const void* __restrict__ W_feat,
        const void* __restrict__ gg, const void* __restrict__ bb, float* ws) {
    __shared__ __align__(16) char SM_[54032];
    __shared__ int sflag;
    int tid = threadIdx.x, bid = blockIdx.x;
    const int isf = detect_isf<NTHR>((const unsigned int*)adj, tid, &sflag);
    if (bid < 512)
        gemm_core<FF, 0>(SM_, tid, isf, bid, x, W_feat, gg, bb, 0, ws);
    unsigned short* CB = (unsigned short*)(SM_ + 52992);
    int* CNT4 = (int*)(SM_ + 54016);
    for (int p = bid; p < 4096; p += 768)
        graph_task(p, tid, isf, CNT4, CB, adj, ws);
}

// ================= K3-5: per-layer gemm + spmm with handshake ===============
// grid 512 = 2 blocks/CU exactly (co-resident). Block: gemm tile bid,
// flag release; then bid<384: spmm task bid (spin on its batch's 32 tiles).
// LDS: WB/Zs union 73728 ; AF/CF/BSUM @73728.. ; total 77568 -> 2 blocks/CU.
__global__ __launch_bounds__(NTHR, 4) void k_layer(const void* __restrict__ adj,
        const void* __restrict__ convs_W, const void* __restrict__ gg,
        const void* __restrict__ bb, const void* __restrict__ convs_b,
        int layer, float* ws) {
    __shared__ __align__(16) char SM_[77568];
    __shared__ int sflag;
    int tid = threadIdx.x, bid = blockIdx.x;
    const int isf = detect_isf<NTHR>((const unsigned int*)adj, tid, &sflag);
    gemm_core<HH, 1>(SM_, tid, isf, bid, (const void*)(ws + OFF_H0),
                     convs_W, gg, bb, layer, ws);
    if (bid >= 384) return;
    // ---------------- spmm task ----------------
    int t = bid;
    int batch = t & 15, rest = t >> 4;
    int slice = rest % 6, qtr = rest / 6;
    int c0 = slice*32;
    {
        int* fl = (int*)(ws + OFF_FLG) + layer*16 + batch;
        if (tid == 0) {
            while (__hip_atomic_load(fl, __ATOMIC_RELAXED, __HIP_MEMORY_SCOPE_AGENT) < 32)
                __builtin_amdgcn_s_sleep(8);
            (void)__hip_atomic_load(fl, __ATOMIC_ACQUIRE, __HIP_MEMORY_SCOPE_AGENT);
        }
        __syncthreads();
    }
    unsigned int* Zs = (unsigned int*)SM_;            // [NN][18] padded
    const float* dis = ws + OFF_DIS;
    const int* cnt = (const int*)(ws + OFF_CNT);
    const unsigned short* cols = (const unsigned short*)(ws + OFF_COLS);
    unsigned int* H0u = (unsigned int*)(ws + OFF_H0);
    const int is_pool = (layer == 2);
    int d = tid & 7, rslot = tid >> 3;
    const unsigned int* Zu = (const unsigned int*)(ws + OFF_ZB)
                             + (size_t)batch*NN*96 + c0/2;
    for (int i4 = tid; i4 < NN*4; i4 += NTHR) {
        int r = i4 >> 2, u0 = (i4 & 3)*4;
        u32x4 v = *(const u32x4*)(Zu + (size_t)r*96 + u0);
        *(u32x2*)(&Zs[r*18 + u0])     = u32x2{v[0], v[1]};
        *(u32x2*)(&Zs[r*18 + u0 + 2]) = u32x2{v[2], v[3]};
    }
    __syncthreads();
    float bch[4];
    #pragma unroll
    for (int e = 0; e < 4; ++e)
        bch[e] = ldin(convs_b, (size_t)layer*HH + c0 + d*4 + e, isf);
    float s_acc[4] = {0.f,0.f,0.f,0.f}, q_acc[4] = {0.f,0.f,0.f,0.f};
    for (int it = 0; it < 4; ++it) {
        int row = batch*NN + qtr*256 + it*64 + rslot;
        int c = cnt[row];
        const unsigned short* cl = cols + (size_t)row*MAXC;
        float a0=0.f, a1=0.f, a2=0.f, a3=0.f;
        int k = 0;
        for (; k + 8 <= c; k += 8) {
            u32x4 cw = *(const u32x4*)(cl + k);
            int j[8];
            j[0]=(int)(cw[0]&0xFFFFu); j[1]=(int)(cw[0]>>16);
            j[2]=(int)(cw[1]&0xFFFFu); j[3]=(int)(cw[1]>>16);
            j[4]=(int)(cw[2]&0xFFFFu); j[5]=(int)(cw[2]>>16);
            j[6]=(int)(cw[3]&0xFFFFu); j[7]=(int)(cw[3]>>16);
            u32x2 z[8];
            #pragma unroll
            for (int e = 0; e < 8; ++e)
                z[e] = *(const u32x2*)(&Zs[j[e]*18 + d*2]);
            #pragma unroll
            for (int e = 0; e < 8; ++e) {
                a0 += blo(z[e][0]); a1 += bhi(z[e][0]);
                a2 += blo(z[e][1]); a3 += bhi(z[e][1]);
            }
        }
        for (; k < c; ++k) {
            u32x2 z = *(const u32x2*)(&Zs[(int)cl[k]*18 + d*2]);
            a0 += blo(z[0]); a1 += bhi(z[0]);
            a2 += blo(z[1]); a3 += bhi(z[1]);
        }
        float dd = dis[row];
        float o0 = fmaxf(dd*a0 + bch[0], 0.f);
        float o1 = fmaxf(dd*a1 + bch[1], 0.f);
        float o2 = fmaxf(dd*a2 + bch[2], 0.f);
        float o3 = fmaxf(dd*a3 + bch[3], 0.f);
        u32x2 outw; outw[0] = packbf(o0,o1); outw[1] = packbf(o2,o3);
        *(u32x2*)(&H0u[(size_t)row*96 + c0/2 + d*2]) = outw;
        s_acc[0]+=o0; s_acc[1]+=o1; s_acc[2]+=o2; s_acc[3]+=o3;
        q_acc[0]+=o0*o0; q_acc[1]+=o1*o1; q_acc[2]+=o2*o2; q_acc[3]+=o3*o3;
    }
    #pragma unroll
    for (int e = 0; e < 4; ++e) {
        #pragma unroll
        for (int mask = 8; mask < 64; mask <<= 1) {
            s_acc[e] += __shfl_xor(s_acc[e], mask, 64);
            q_acc[e] += __shfl_xor(q_acc[e], mask, 64);
        }
    }
    if ((tid & 63) < 8) {
        if (is_pool) {
            #pragma unroll
            for (int e = 0; e < 4; ++e)
                atomicAdd(&ws[OFF_G + (size_t)batch*HH + c0 + d*4 + e], s_acc[e]);
        } else {
            float* st = ws + OFF_SH + (size_t)(layer + 1)*4096 + (size_t)(t & 7)*512;
            #pragma unroll
            for (int e = 0; e < 4; ++e) {
                atomicAdd(&st[c0 + d*4 + e],       s_acc[e]);
                atomicAdd(&st[256 + c0 + d*4 + e], q_acc[e]);
            }
        }
    }
}

// ================= K6 tail ==================================================
// LDS: Wl bf16 @0 (36864) ; G1 @36864 ; G2 @49152 ; LG @61440 ; LSE @62080
__global__ __launch_bounds__(NTHR, 4) void k_tail(const void* __restrict__ adj,
        const void* fc_g, const void* fc_b, const void* lin_W, const void* lin_b,
        const void* hid_g, const void* hid_b, const void* cls_W, const void* cls_b,
        void* out, const float* ws) {
    __shared__ __align__(16) char SM_[62144];
    __shared__ int sflag;
    int tid = threadIdx.x;
    const int isf = detect_isf<NTHR>((const unsigned int*)adj, tid, &sflag);
    __hip_bfloat16* Wl = (__hip_bfloat16*)SM_;
    float* G1  = (float*)(SM_ + 36864);
    float* G2  = (float*)(SM_ + 49152);
    float* LG  = (float*)(SM_ + 61440);
    float* LSE = (float*)(SM_ + 62080);
    const float* g = ws + OFF_G;
    if (tid < HH) {
        float s = 0.f, sq = 0.f;
        for (int b = 0; b < BB; ++b) {
            float v = g[b*HH + tid]*(1.f/NN);
            s += v; sq += v*v;
        }
        float mean = s*(1.f/BB), var = sq*(1.f/BB) - mean*mean;
        float a = ldin(fc_g, tid, isf) * rsqrtf(var + EPSV);
        float c = ldin(fc_b, tid, isf) - mean*a;
        for (int b = 0; b < BB; ++b) G1[b*HH + tid] = g[b*HH + tid]*(1.f/NN)*a + c;
    }
    int b = tid >> 5, grp = tid & 31, n0 = grp*6;
    float acc[6];
    #pragma unroll
    for (int e = 0; e < 6; ++e) acc[e] = ldin(lin_b, n0 + e, isf);
    for (int ch = 0; ch < 2; ++ch) {
        __syncthreads();
        if (isf) {
            const f32x4* Wp = (const f32x4*)lin_W + (size_t)ch*96*HH/4;
            for (int i = tid; i < 96*HH/8; i += NTHR) {
                f32x4 v0 = Wp[2*i], v1 = Wp[2*i + 1];
                union { short8 s8; __hip_bfloat16 h[8]; } u;
                #pragma unroll
                for (int e = 0; e < 4; ++e) {
                    u.h[e]   = __float2bfloat16(v0[e]);
                    u.h[e+4] = __float2bfloat16(v1[e]);
                }
                *(short8*)&Wl[8*i] = u.s8;
            }
        } else {
            const short8* Wp = (const short8*)lin_W + (size_t)ch*96*HH/8;
            for (int i = tid; i < 96*HH/8; i += NTHR)
                *(short8*)&Wl[8*i] = Wp[i];
        }
        __syncthreads();
        for (int k = 0; k < 96; ++k) {
            float gv = G1[b*HH + ch*96 + k];
            const unsigned int* wp = (const unsigned int*)&Wl[k*HH + n0];
            unsigned int w0 = wp[0], w1 = wp[1], w2 = wp[2];
            acc[0] += gv*blo(w0); acc[1] += gv*bhi(w0);
            acc[2] += gv*blo(w1); acc[3] += gv*bhi(w1);
            acc[4] += gv*blo(w2); acc[5] += gv*bhi(w2);
        }
    }
    __syncthreads();
    #pragma unroll
    for (int e = 0; e < 6; ++e) G2[b*HH + n0 + e] = fmaxf(acc[e], 0.f);
    __syncthreads();
    if (tid < HH) {
        float s = 0.f, sq = 0.f;
        for (int bb = 0; bb < BB; ++bb) { float v = G2[bb*HH + tid]; s += v; sq += v*v; }
        float mean = s*(1.f/BB), var = sq*(1.f/BB) - mean*mean;
        float a = ldin(hid_g, tid, isf) * rsqrtf(var + EPSV);
        float c = ldin(hid_b, tid, isf) - mean*a;
        for (int bb = 0; bb < BB; ++bb) G2[bb*HH + tid] = G2[bb*HH + tid]*a + c;
    }
    __syncthreads();
    if (tid < BB*10) {
        int bb = tid/10, kk = tid%10;
        float a2 = ldin(cls_b, kk, isf);
        for (int h = 0; h < HH; ++h) a2 += G2[bb*HH + h]*ldin(cls_W, (size_t)h*10 + kk, isf);
        LG[bb*10 + kk] = a2;
    }
    __syncthreads();
    if (tid < BB) {
        float mx = -1e30f;
        for (int k = 0; k < 10; ++k) mx = fmaxf(mx, LG[tid*10 + k]);
        float s = 0.f;
        for (int k = 0; k < 10; ++k) s += expf(LG[tid*10 + k] - mx);
        LSE[tid] = mx + logf(s);
    }
    __syncthreads();
    if (tid < BB*10) {
        int bb = tid/10;
        float v = LG[bb*10 + tid%10] - LSE[bb];
        if (isf) ((float*)out)[tid] = v;
        else     ((__hip_bfloat16*)out)[tid] = __float2bfloat16(v);
    }
}

extern "C" void kernel_launch(void* const* d_in, const int* in_sizes, int n_in,
                              void* d_out, int out_size, void* d_ws, size_t ws_size,
                              hipStream_t stream) {
    const void* x       = d_in[0];
    const void* adj     = d_in[1];
    const void* bnf_g   = d_in[2];
    const void* bnf_b   = d_in[3];
    const void* W_feat  = d_in[4];
    const void* bnc_g   = d_in[5];
    const void* bnc_b   = d_in[6];
    const void* convs_W = d_in[7];
    const void* convs_b = d_in[8];
    const void* fc_g    = d_in[9];
    const void* fc_b    = d_in[10];
    const void* lin_W   = d_in[11];
    const void* lin_b   = d_in[12];
    const void* hid_g   = d_in[13];
    const void* hid_b   = d_in[14];
    const void* cls_W   = d_in[15];
    const void* cls_b   = d_in[16];
    float* ws = (float*)d_ws;

    k_prep<<<96, NTHR, 0, stream>>>(adj, x, ws);
    k_gg0<<<768, NTHR, 0, stream>>>(adj, x, W_feat, bnf_g, bnf_b, ws);
    for (int l = 0; l < 3; ++l)
        k_layer<<<512, NTHR, 0, stream>>>(adj, convs_W, bnc_g, bnc_b, convs_b, l, ws);
    k_tail<<<1, NTHR, 0, stream>>>(adj, fc_g, fc_b, lin_W, lin_b,
                                   hid_g, hid_b, cls_W, cls_b, d_out, ws);
}

// Round 5
// 314.870 us; speedup vs baseline: 1.1989x; 1.1989x over previous
//
#include <hip/hip_runtime.h>
#include <hip/hip_bf16.h>

#define BB 16
#define NN 1024
#define FF 128
#define HH 192
#define NROWS (BB*NN)
#define MAXC 128
#define EPSV 1e-5f

// ---------------- workspace layout (float units) ----------------
constexpr size_t OFF_H0  = 0;                                 // [NROWS*HH] bf16
constexpr size_t OFF_ZB  = OFF_H0 + (size_t)NROWS*HH/2;       // [NROWS*HH] bf16
constexpr size_t OFF_DIS = OFF_ZB + (size_t)NROWS*HH/2;       // [NROWS] f32
constexpr size_t OFF_G   = OFF_DIS + NROWS;                   // [BB*HH] pool sums
constexpr size_t OFF_SH  = OFF_G + BB*HH;                     // 3 stages x 8 buckets x 512
constexpr size_t SH_SIZE = 3*8*512;
constexpr size_t ZERO_SZ = BB*HH + SH_SIZE;                   // zeroed in k_prep
constexpr size_t OFF_XB  = OFF_SH + SH_SIZE;                  // x-stat buckets [64][256]
constexpr size_t OFF_WPF = OFF_XB + 64*256;                   // [192*128] bf16 feat W'T
constexpr size_t OFF_WPC = OFF_WPF + (size_t)HH*FF/2;         // [192*192] bf16 conv W'T
constexpr size_t OFF_BF  = OFF_WPC + (size_t)HH*HH/2;         // [192] f32
constexpr size_t OFF_BC  = OFF_BF + HH;                       // [192] f32
constexpr size_t OFF_CNT = OFF_BC + HH;                       // [NROWS] int32
constexpr size_t OFF_COLS= OFF_CNT + NROWS;                   // [NROWS*MAXC] u16

typedef __attribute__((ext_vector_type(8))) short short8;
typedef __attribute__((ext_vector_type(4))) float f32x4;
typedef __attribute__((ext_vector_type(4))) unsigned int u32x4;
typedef __attribute__((ext_vector_type(2))) unsigned int u32x2;

static __device__ __forceinline__ float ldin(const void* p, size_t i, int isf) {
    return isf ? ((const float*)p)[i]
               : __bfloat162float(((const __hip_bfloat16*)p)[i]);
}
static __device__ __forceinline__ float blo(unsigned int u) {
    union { unsigned int x; float f; } v; v.x = u << 16; return v.f;
}
static __device__ __forceinline__ float bhi(unsigned int u) {
    union { unsigned int x; float f; } v; v.x = u & 0xFFFF0000u; return v.f;
}
static __device__ __forceinline__ unsigned int packbf(float a, float b) {
    union { unsigned int u; __hip_bfloat16 h[2]; } p;
    p.h[0] = __float2bfloat16(a); p.h[1] = __float2bfloat16(b);
    return p.u;
}
static __device__ __forceinline__ unsigned short bf16bits(float a) {
    union { unsigned short u; __hip_bfloat16 h; } p;
    p.h = __float2bfloat16(a); return p.u;
}

// dtype self-detection (adj elements exactly {0,1}) — 4 KB L2-hot scan.
template<int T>
static __device__ __forceinline__ int detect_isf(const unsigned int* __restrict__ adjw,
                                                 int tid, int* sh_flag) {
    if (tid == 0) *sh_flag = 0;
    __syncthreads();
    int hit = 0;
    for (int k = tid; k < 1024; k += T)
        if ((adjw[k] & 0xFFFFu) == 0x3F80u) hit = 1;
    if (hit) *sh_flag = 1;
    __syncthreads();
    return (*sh_flag == 0) ? 1 : 0;
}

// ================= K1: zero stat regions + x-stats (64 buckets) =============
__global__ __launch_bounds__(512) void k_prep(const void* __restrict__ adj,
                                              const void* __restrict__ x, float* ws) {
    __shared__ __align__(16) float XS[1024];
    __shared__ int sflag;
    int tid = threadIdx.x, bid = blockIdx.x;
    const int isf = detect_isf<512>((const unsigned int*)adj, tid, &sflag);
    for (size_t i = (size_t)bid*512 + tid; i < ZERO_SZ; i += (size_t)96*512)
        ws[OFF_G + i] = 0.f;
    if (bid < 64) {
        int f = tid & 127, part = tid >> 7;           // 4 parts x 64 rows
        int r0 = bid*256 + part*64;
        float s = 0.f, q = 0.f;
        for (int r = 0; r < 64; ++r) {
            float v = ldin(x, (size_t)(r0 + r)*FF + f, isf);
            s += v; q += v*v;
        }
        XS[part*128 + f] = s; XS[512 + part*128 + f] = q;
        __syncthreads();
        if (part == 0) {
            ws[OFF_XB + (size_t)bid*256 + f] =
                XS[f] + XS[128+f] + XS[256+f] + XS[384+f];
            ws[OFF_XB + (size_t)bid*256 + 128 + f] =
                XS[512+f] + XS[640+f] + XS[768+f] + XS[896+f];
        }
    }
}

// ================= K2: fold feat W (once) ===================================
__global__ __launch_bounds__(128) void k_fold0(const void* __restrict__ adj,
        const void* __restrict__ W_feat, const void* __restrict__ gg,
        const void* __restrict__ bb, float* ws) {
    __shared__ float red[FF];
    __shared__ int sflag;
    int n = blockIdx.x, k = threadIdx.x;
    const int isf = detect_isf<128>((const unsigned int*)adj, k, &sflag);
    float s = 0.f, q = 0.f;
    for (int b = 0; b < 64; ++b) {
        s += ws[OFF_XB + (size_t)b*256 + k];
        q += ws[OFF_XB + (size_t)b*256 + 128 + k];
    }
    float m   = s * (1.f/NROWS);
    float var = q * (1.f/NROWS) - m*m;
    float a   = ldin(gg, k, isf) * rsqrtf(var + EPSV);
    float c   = ldin(bb, k, isf) - m*a;
    float wv  = ldin(W_feat, (size_t)k*HH + n, isf);
    ((__hip_bfloat16*)(ws + OFF_WPF))[(size_t)n*FF + k] = __float2bfloat16(a*wv);
    red[k] = c*wv;
    __syncthreads();
    for (int s2 = FF/2; s2 > 0; s2 >>= 1) {
        if (k < s2) red[k] += red[k + s2];
        __syncthreads();
    }
    if (k == 0) ws[OFF_BF + n] = red[0];
}

// ================= K per-layer: fold conv W (once) ==========================
__global__ __launch_bounds__(192) void k_foldc(const void* __restrict__ adj,
        const void* __restrict__ convs_W, const void* __restrict__ gg,
        const void* __restrict__ bb, int layer, float* ws) {
    __shared__ float red[HH];
    __shared__ int sflag;
    int n = blockIdx.x, k = threadIdx.x;
    const int isf = detect_isf<192>((const unsigned int*)adj, k, &sflag);
    const float* st = ws + OFF_SH + (size_t)layer*4096;
    float s = 0.f, q = 0.f;
    #pragma unroll
    for (int b = 0; b < 8; ++b) {
        s += st[b*512 + k];
        q += st[b*512 + 256 + k];
    }
    float m   = s * (1.f/NROWS);
    float var = q * (1.f/NROWS) - m*m;
    float a   = ldin(gg, (size_t)layer*HH + k, isf) * rsqrtf(var + EPSV);
    float c   = ldin(bb, (size_t)layer*HH + k, isf) - m*a;
    float wv  = ldin(convs_W, (size_t)layer*HH*HH + (size_t)k*HH + n, isf);
    ((__hip_bfloat16*)(ws + OFF_WPC))[(size_t)n*HH + k] = __float2bfloat16(a*wv);
    red[k] = c*wv;
    __syncthreads();
    if (k < 96) red[k] += red[k + 96];
    __syncthreads();
    for (int s2 = 48; s2 >= 3; s2 >>= 1) {
        if (k < s2) red[k] += red[k + s2];
        __syncthreads();
    }
    if (k == 0) ws[OFF_BC + n] = red[0] + red[1] + red[2];
}

// ================= K3: gemm0 (blocks<1024) + graph build (rest) =============
// gemm0: 16-row x 192-col tile, 4 waves x (16r x 48c), B = WPF from L2.
// graph: blocks>=1024: 2 adj rows per block (128 lanes each).
__global__ __launch_bounds__(256, 4) void k_gg0(const void* __restrict__ adj,
        const void* __restrict__ x, float* ws) {
    __shared__ __align__(16) float SH2[384];
    __shared__ int CNT2[2];
    __shared__ unsigned short CB[2][MAXC];
    __shared__ int sflag;
    int tid = threadIdx.x, bid = blockIdx.x;
    const int isf = detect_isf<256>((const unsigned int*)adj, tid, &sflag);
    if (bid < 1024) {
        // ---------------- gemm0 ----------------
        for (int i = tid; i < 384; i += 256) SH2[i] = 0.f;
        __syncthreads();
        int lane = tid & 63, wc = tid >> 6;
        int m = lane & 15, quad = lane >> 4;
        int batch = bid & 15, seg = bid >> 4;
        int row0 = batch*NN + seg*16;
        const __hip_bfloat16* BT = (const __hip_bfloat16*)(ws + OFF_WPF);
        float bv[3];
        #pragma unroll
        for (int tt = 0; tt < 3; ++tt) bv[tt] = ws[OFF_BF + wc*48 + tt*16 + m];
        f32x4 acc[3];
        #pragma unroll
        for (int tt = 0; tt < 3; ++tt) acc[tt] = f32x4{0.f,0.f,0.f,0.f};
        int rowA = row0 + m;
        #pragma unroll
        for (int kb = 0; kb < FF/32; ++kb) {
            short8 a;
            if (isf) {
                const float* Ar = (const float*)x + (size_t)rowA*FF + kb*32 + quad*8;
                f32x4 v0 = *(const f32x4*)Ar, v1 = *(const f32x4*)(Ar + 4);
                union { short8 s8; __hip_bfloat16 h[8]; } u;
                #pragma unroll
                for (int e = 0; e < 4; ++e) {
                    u.h[e]   = __float2bfloat16(v0[e]);
                    u.h[e+4] = __float2bfloat16(v1[e]);
                }
                a = u.s8;
            } else {
                a = *(const short8*)((const __hip_bfloat16*)x +
                                     (size_t)rowA*FF + kb*32 + quad*8);
            }
            #pragma unroll
            for (int tt = 0; tt < 3; ++tt) {
                short8 b = *(const short8*)(BT + (size_t)(wc*48 + tt*16 + m)*FF +
                                            kb*32 + quad*8);
                acc[tt] = __builtin_amdgcn_mfma_f32_16x16x32_bf16(a, b, acc[tt], 0, 0, 0);
            }
        }
        __hip_bfloat16* H0 = (__hip_bfloat16*)(ws + OFF_H0);
        #pragma unroll
        for (int tt = 0; tt < 3; ++tt) {
            int nl = wc*48 + tt*16 + m;
            float s = 0.f, sq = 0.f;
            #pragma unroll
            for (int r = 0; r < 4; ++r) {
                int row = row0 + quad*4 + r;
                float o = fmaxf(acc[tt][r] + bv[tt], 0.f);
                H0[(size_t)row*HH + nl] = __float2bfloat16(o);
                s += o; sq += o*o;
            }
            s  += __shfl_xor(s, 16, 64);  s  += __shfl_xor(s, 32, 64);
            sq += __shfl_xor(sq, 16, 64); sq += __shfl_xor(sq, 32, 64);
            if (quad == 0) {
                atomicAdd(&SH2[nl], s);
                atomicAdd(&SH2[192 + nl], sq);
            }
        }
        __syncthreads();
        float* st = ws + OFF_SH + (size_t)(bid & 7)*512;
        if (tid < 192) {
            atomicAdd(&st[tid], SH2[tid]);
            atomicAdd(&st[256 + tid], SH2[192 + tid]);
        }
    } else {
        // ---------------- graph build: 2 rows ----------------
        int gb = bid - 1024;
        int lane = tid & 127, half = tid >> 7;
        int row = gb*2 + half;
        int i = row & (NN - 1);
        if (lane == 0) CNT2[half] = 0;
        __syncthreads();
        int j0 = lane*8;
        unsigned int bits[8];
        if (isf) {
            const unsigned int* ap = (const unsigned int*)adj + (size_t)row*NN + j0;
            u32x4 v0 = *(const u32x4*)ap;
            u32x4 v1 = *(const u32x4*)(ap + 4);
            bits[0]=v0[0]; bits[1]=v0[1]; bits[2]=v0[2]; bits[3]=v0[3];
            bits[4]=v1[0]; bits[5]=v1[1]; bits[6]=v1[2]; bits[7]=v1[3];
        } else {
            const unsigned short* ap = (const unsigned short*)adj + (size_t)row*NN + j0;
            u32x4 v = *(const u32x4*)ap;
            #pragma unroll
            for (int e = 0; e < 4; ++e) { bits[2*e] = v[e] & 0xFFFFu; bits[2*e+1] = v[e] >> 16; }
        }
        #pragma unroll
        for (int e = 0; e < 8; ++e) {
            int j = j0 + e;
            if ((bits[e] << 1) != 0u || j == i) {
                int p2 = atomicAdd(&CNT2[half], 1);
                if (p2 < MAXC) CB[half][p2] = (unsigned short)j;
            }
        }
        __syncthreads();
        int c = CNT2[half];
        int cc = c > MAXC ? MAXC : c;
        if (lane == 0) {
            ((int*)(ws + OFF_CNT))[row] = cc;
            ws[OFF_DIS + row] = rsqrtf((float)c);     // deg >= 1 (self loop)
        }
        unsigned short* cols = (unsigned short*)(ws + OFF_COLS);
        for (int k = lane; k < cc; k += 128) cols[(size_t)row*MAXC + k] = CB[half][k];
    }
}

// ================= K per-layer: lean conv gemm ==============================
// 16-row x 192-col tile; A = H0 bf16, B = WPC from L2; out Z = (acc+BC)*dis.
__global__ __launch_bounds__(256, 4) void k_gemmc(float* __restrict__ ws) {
    __shared__ __align__(16) unsigned short ZT[16*HH];
    int tid = threadIdx.x, bid = blockIdx.x;
    int lane = tid & 63, wc = tid >> 6;
    int m = lane & 15, quad = lane >> 4;
    int batch = bid & 15, seg = bid >> 4;
    int row0 = batch*NN + seg*16;
    const __hip_bfloat16* A = (const __hip_bfloat16*)(ws + OFF_H0);
    const __hip_bfloat16* BT = (const __hip_bfloat16*)(ws + OFF_WPC);
    float bv[3];
    #pragma unroll
    for (int tt = 0; tt < 3; ++tt) bv[tt] = ws[OFF_BC + wc*48 + tt*16 + m];
    f32x4 acc[3];
    #pragma unroll
    for (int tt = 0; tt < 3; ++tt) acc[tt] = f32x4{0.f,0.f,0.f,0.f};
    int rowA = row0 + m;
    #pragma unroll
    for (int kb = 0; kb < HH/32; ++kb) {
        short8 a = *(const short8*)(A + (size_t)rowA*HH + kb*32 + quad*8);
        #pragma unroll
        for (int tt = 0; tt < 3; ++tt) {
            short8 b = *(const short8*)(BT + (size_t)(wc*48 + tt*16 + m)*HH +
                                        kb*32 + quad*8);
            acc[tt] = __builtin_amdgcn_mfma_f32_16x16x32_bf16(a, b, acc[tt], 0, 0, 0);
        }
    }
    const float* dis = ws + OFF_DIS;
    float sc[4];
    #pragma unroll
    for (int r = 0; r < 4; ++r) sc[r] = dis[row0 + quad*4 + r];
    #pragma unroll
    for (int tt = 0; tt < 3; ++tt) {
        int nl = wc*48 + tt*16 + m;
        #pragma unroll
        for (int r = 0; r < 4; ++r)
            ZT[(quad*4 + r)*HH + nl] = bf16bits((acc[tt][r] + bv[tt])*sc[r]);
    }
    __syncthreads();
    unsigned int* Zg = (unsigned int*)(ws + OFF_ZB) + (size_t)row0*96;
    const unsigned int* ZTu = (const unsigned int*)ZT;
    #pragma unroll
    for (int ii = 0; ii < 3; ++ii) {
        int i = tid + ii*256;
        *(u32x2*)(&Zg[2*i]) = *(const u32x2*)(&ZTu[2*i]);
    }
}

// ================= K per-layer: spmm direct-from-L2 =========================
// grid 3072 = 16 batch x 6 slice x 32 rowgroup; block 256 = 32 rows x 8 lanes.
// Each 8-lane unit gathers one (row, 32-ch slice): neighbor = one 64B L2 line.
__global__ __launch_bounds__(256, 6) void k_spmm(const void* __restrict__ adj,
        const void* __restrict__ convs_b, int layer, float* __restrict__ ws) {
    __shared__ float SH[64];
    __shared__ int sflag;
    int tid = threadIdx.x, bid = blockIdx.x;
    const int isf = detect_isf<256>((const unsigned int*)adj, tid, &sflag);
    for (int i = tid; i < 64; i += 256) SH[i] = 0.f;
    int batch = bid / 192, rem = bid - batch*192;
    int slice = rem >> 5, rg = rem & 31;
    int u = tid >> 3, d = tid & 7;
    int row = batch*NN + rg*32 + u;
    int c0 = slice*32;
    int base = slice*16 + d*2;
    const int c = ((const int*)(ws + OFF_CNT))[row];
    const unsigned short* cl = (const unsigned short*)(ws + OFF_COLS) + (size_t)row*MAXC;
    const unsigned int* Zb = (const unsigned int*)(ws + OFF_ZB) + (size_t)batch*NN*96;
    float bch[4];
    #pragma unroll
    for (int e = 0; e < 4; ++e)
        bch[e] = ldin(convs_b, (size_t)layer*HH + c0 + d*4 + e, isf);
    float a0=0.f, a1=0.f, a2=0.f, a3=0.f;
    int k = 0;
    for (; k + 8 <= c; k += 8) {
        u32x4 cw = *(const u32x4*)(cl + k);
        int j[8];
        j[0]=(int)(cw[0]&0xFFFFu); j[1]=(int)(cw[0]>>16);
        j[2]=(int)(cw[1]&0xFFFFu); j[3]=(int)(cw[1]>>16);
        j[4]=(int)(cw[2]&0xFFFFu); j[5]=(int)(cw[2]>>16);
        j[6]=(int)(cw[3]&0xFFFFu); j[7]=(int)(cw[3]>>16);
        u32x2 z[8];
        #pragma unroll
        for (int e = 0; e < 8; ++e)
            z[e] = *(const u32x2*)(&Zb[(size_t)j[e]*96 + base]);
        #pragma unroll
        for (int e = 0; e < 8; ++e) {
            a0 += blo(z[e][0]); a1 += bhi(z[e][0]);
            a2 += blo(z[e][1]); a3 += bhi(z[e][1]);
        }
    }
    for (; k < c; ++k) {
        u32x2 z = *(const u32x2*)(&Zb[(size_t)cl[k]*96 + base]);
        a0 += blo(z[0]); a1 += bhi(z[0]);
        a2 += blo(z[1]); a3 += bhi(z[1]);
    }
    float dd = ws[OFF_DIS + row];
    float o0 = fmaxf(dd*a0 + bch[0], 0.f);
    float o1 = fmaxf(dd*a1 + bch[1], 0.f);
    float o2 = fmaxf(dd*a2 + bch[2], 0.f);
    float o3 = fmaxf(dd*a3 + bch[3], 0.f);
    unsigned int* H0u = (unsigned int*)(ws + OFF_H0);
    u32x2 outw; outw[0] = packbf(o0,o1); outw[1] = packbf(o2,o3);
    *(u32x2*)(&H0u[(size_t)row*96 + base]) = outw;
    // ---- stats (layers 0,1: stage l+1; layer 2: pool sums) ----
    float s_acc[4] = {o0,o1,o2,o3};
    float q_acc[4] = {o0*o0,o1*o1,o2*o2,o3*o3};
    const int is_pool = (layer == 2);
    #pragma unroll
    for (int e = 0; e < 4; ++e) {
        #pragma unroll
        for (int mask = 8; mask < 64; mask <<= 1) {
            s_acc[e] += __shfl_xor(s_acc[e], mask, 64);
            if (!is_pool) q_acc[e] += __shfl_xor(q_acc[e], mask, 64);
        }
    }
    __syncthreads();
    if ((tid & 63) < 8) {
        #pragma unroll
        for (int e = 0; e < 4; ++e) {
            atomicAdd(&SH[d*4 + e], s_acc[e]);
            if (!is_pool) atomicAdd(&SH[32 + d*4 + e], q_acc[e]);
        }
    }
    __syncthreads();
    if (tid < 32) {
        if (is_pool) {
            atomicAdd(&ws[OFF_G + (size_t)batch*HH + c0 + tid], SH[tid]);
        } else {
            float* st = ws + OFF_SH + (size_t)(layer + 1)*4096 + (size_t)(bid & 7)*512;
            atomicAdd(&st[c0 + tid],       SH[tid]);
            atomicAdd(&st[256 + c0 + tid], SH[32 + tid]);
        }
    }
}

// ================= tail =====================================================
__global__ __launch_bounds__(512) void k_tail(const void* __restrict__ adj,
        const void* fc_g, const void* fc_b, const void* lin_W, const void* lin_b,
        const void* hid_g, const void* hid_b, const void* cls_W, const void* cls_b,
        void* out, const float* ws) {
    __shared__ __align__(16) char SM_[62144];
    __shared__ int sflag;
    int tid = threadIdx.x;
    const int isf = detect_isf<512>((const unsigned int*)adj, tid, &sflag);
    __hip_bfloat16* Wl = (__hip_bfloat16*)SM_;
    float* G1  = (float*)(SM_ + 36864);
    float* G2  = (float*)(SM_ + 49152);
    float* LG  = (float*)(SM_ + 61440);
    float* LSE = (float*)(SM_ + 62080);
    const float* g = ws + OFF_G;
    if (tid < HH) {
        float s = 0.f, sq = 0.f;
        for (int b = 0; b < BB; ++b) {
            float v = g[b*HH + tid]*(1.f/NN);
            s += v; sq += v*v;
        }
        float mean = s*(1.f/BB), var = sq*(1.f/BB) - mean*mean;
        float a = ldin(fc_g, tid, isf) * rsqrtf(var + EPSV);
        float c = ldin(fc_b, tid, isf) - mean*a;
        for (int b = 0; b < BB; ++b) G1[b*HH + tid] = g[b*HH + tid]*(1.f/NN)*a + c;
    }
    int b = tid >> 5, grp = tid & 31, n0 = grp*6;
    float acc[6];
    #pragma unroll
    for (int e = 0; e < 6; ++e) acc[e] = ldin(lin_b, n0 + e, isf);
    for (int ch = 0; ch < 2; ++ch) {
        __syncthreads();
        if (isf) {
            const f32x4* Wp = (const f32x4*)lin_W + (size_t)ch*96*HH/4;
            for (int i = tid; i < 96*HH/8; i += 512) {
                f32x4 v0 = Wp[2*i], v1 = Wp[2*i + 1];
                union { short8 s8; __hip_bfloat16 h[8]; } u;
                #pragma unroll
                for (int e = 0; e < 4; ++e) {
                    u.h[e]   = __float2bfloat16(v0[e]);
                    u.h[e+4] = __float2bfloat16(v1[e]);
                }
                *(short8*)&Wl[8*i] = u.s8;
            }
        } else {
            const short8* Wp = (const short8*)lin_W + (size_t)ch*96*HH/8;
            for (int i = tid; i < 96*HH/8; i += 512)
                *(short8*)&Wl[8*i] = Wp[i];
        }
        __syncthreads();
        for (int k = 0; k < 96; ++k) {
            float gv = G1[b*HH + ch*96 + k];
            const unsigned int* wp = (const unsigned int*)&Wl[k*HH + n0];
            unsigned int w0 = wp[0], w1 = wp[1], w2 = wp[2];
            acc[0] += gv*blo(w0); acc[1] += gv*bhi(w0);
            acc[2] += gv*blo(w1); acc[3] += gv*bhi(w1);
            acc[4] += gv*blo(w2); acc[5] += gv*bhi(w2);
        }
    }
    __syncthreads();
    #pragma unroll
    for (int e = 0; e < 6; ++e) G2[b*HH + n0 + e] = fmaxf(acc[e], 0.f);
    __syncthreads();
    if (tid < HH) {
        float s = 0.f, sq = 0.f;
        for (int bb = 0; bb < BB; ++bb) { float v = G2[bb*HH + tid]; s += v; sq += v*v; }
        float mean = s*(1.f/BB), var = sq*(1.f/BB) - mean*mean;
        float a = ldin(hid_g, tid, isf) * rsqrtf(var + EPSV);
        float c = ldin(hid_b, tid, isf) - mean*a;
        for (int bb = 0; bb < BB; ++bb) G2[bb*HH + tid] = G2[bb*HH + tid]*a + c;
    }
    __syncthreads();
    if (tid < BB*10) {
        int bb = tid/10, kk = tid%10;
        float a2 = ldin(cls_b, kk, isf);
        for (int h = 0; h < HH; ++h) a2 += G2[bb*HH + h]*ldin(cls_W, (size_t)h*10 + kk, isf);
        LG[bb*10 + kk] = a2;
    }
    __syncthreads();
    if (tid < BB) {
        float mx = -1e30f;
        for (int k = 0; k < 10; ++k) mx = fmaxf(mx, LG[tid*10 + k]);
        float s = 0.f;
        for (int k = 0; k < 10; ++k) s += expf(LG[tid*10 + k] - mx);
        LSE[tid] = mx + logf(s);
    }
    __syncthreads();
    if (tid < BB*10) {
        int bb = tid/10;
        float v = LG[bb*10 + tid%10] - LSE[bb];
        if (isf) ((float*)out)[tid] = v;
        else     ((__hip_bfloat16*)out)[tid] = __float2bfloat16(v);
    }
}

extern "C" void kernel_launch(void* const* d_in, const int* in_sizes, int n_in,
                              void* d_out, int out_size, void* d_ws, size_t ws_size,
                              hipStream_t stream) {
    const void* x       = d_in[0];
    const void* adj     = d_in[1];
    const void* bnf_g   = d_in[2];
    const void* bnf_b   = d_in[3];
    const void* W_feat  = d_in[4];
    const void* bnc_g   = d_in[5];
    const void* bnc_b   = d_in[6];
    const void* convs_W = d_in[7];
    const void* convs_b = d_in[8];
    const void* fc_g    = d_in[9];
    const void* fc_b    = d_in[10];
    const void* lin_W   = d_in[11];
    const void* lin_b   = d_in[12];
    const void* hid_g   = d_in[13];
    const void* hid_b   = d_in[14];
    const void* cls_W   = d_in[15];
    const void* cls_b   = d_in[16];
    float* ws = (float*)d_ws;

    k_prep<<<96, 512, 0, stream>>>(adj, x, ws);
    k_fold0<<<HH, FF, 0, stream>>>(adj, W_feat, bnf_g, bnf_b, ws);
    k_gg0<<<1024 + 8192, 256, 0, stream>>>(adj, x, ws);
    for (int l = 0; l < 3; ++l) {
        k_foldc<<<HH, HH, 0, stream>>>(adj, convs_W, bnc_g, bnc_b, l, ws);
        k_gemmc<<<1024, 256, 0, stream>>>(ws);
        k_spmm<<<3072, 256, 0, stream>>>(adj, convs_b, l, ws);
    }
    k_tail<<<1, 512, 0, stream>>>(adj, fc_g, fc_b, lin_W, lin_b,
                                  hid_g, hid_b, cls_W, cls_b, d_out, ws);
}

// Round 6
// 300.611 us; speedup vs baseline: 1.2558x; 1.0474x over previous
//
#include <hip/hip_runtime.h>
#include <hip/hip_bf16.h>

#define BB 16
#define NN 1024
#define FF 128
#define HH 192
#define NROWS (BB*NN)
#define MAXC 128
#define EPSV 1e-5f

// ---------------- workspace layout (float units) ----------------
constexpr size_t OFF_H0  = 0;                                 // [NROWS*HH] bf16
constexpr size_t OFF_ZB  = OFF_H0 + (size_t)NROWS*HH/2;       // [NROWS*HH] bf16
constexpr size_t OFF_DIS = OFF_ZB + (size_t)NROWS*HH/2;       // [NROWS] f32
constexpr size_t OFF_G   = OFF_DIS + NROWS;                   // [BB*HH] pool sums
constexpr size_t OFF_SH  = OFF_G + BB*HH;                     // 3 stages x 8 buckets x 512
constexpr size_t SH_SIZE = 3*8*512;
constexpr size_t ZERO_SZ = BB*HH + SH_SIZE;                   // zeroed in k_prep
constexpr size_t OFF_FLG = OFF_SH + SH_SIZE;                  // [16] isf flag
constexpr size_t OFF_PRM = OFF_FLG + 16;                      // f32 params [3584]
// prm: 0 fc_g,192 fc_b,384 lin_b,576 hid_g,768 hid_b,960 cls_b(10),
//      976 cls_W(1920), 2896 convs_b(576)
constexpr size_t OFF_WLT = OFF_PRM + 3584;                    // lin_W bf16 [HH*HH]
constexpr size_t OFF_XB  = OFF_WLT + (size_t)HH*HH/2;         // x-stat buckets [128][256]
constexpr size_t OFF_WPF = OFF_XB + 128*256;                  // [192*128] bf16
constexpr size_t OFF_WPC = OFF_WPF + (size_t)HH*FF/2;         // [192*192] bf16
constexpr size_t OFF_BF  = OFF_WPC + (size_t)HH*HH/2;         // [192] f32
constexpr size_t OFF_BC  = OFF_BF + HH;                       // [192] f32
constexpr size_t OFF_CNT = OFF_BC + HH;                       // [NROWS] int32
constexpr size_t OFF_COLS= OFF_CNT + NROWS;                   // [NROWS*MAXC] u16

typedef __attribute__((ext_vector_type(8))) short short8;
typedef __attribute__((ext_vector_type(4))) float f32x4;
typedef __attribute__((ext_vector_type(4))) unsigned int u32x4;
typedef __attribute__((ext_vector_type(2))) unsigned int u32x2;

static __device__ __forceinline__ float ldin(const void* p, size_t i, int isf) {
    return isf ? ((const float*)p)[i]
               : __bfloat162float(((const __hip_bfloat16*)p)[i]);
}
static __device__ __forceinline__ float blo(unsigned int u) {
    union { unsigned int x; float f; } v; v.x = u << 16; return v.f;
}
static __device__ __forceinline__ float bhi(unsigned int u) {
    union { unsigned int x; float f; } v; v.x = u & 0xFFFF0000u; return v.f;
}
static __device__ __forceinline__ unsigned int packbf(float a, float b) {
    union { unsigned int u; __hip_bfloat16 h[2]; } p;
    p.h[0] = __float2bfloat16(a); p.h[1] = __float2bfloat16(b);
    return p.u;
}
static __device__ __forceinline__ unsigned short bf16bits(float a) {
    union { unsigned short u; __hip_bfloat16 h; } p;
    p.h = __float2bfloat16(a); return p.u;
}
static __device__ __forceinline__ int rdflag(const float* ws) {
    return ((const int*)(ws + OFF_FLG))[0];
}

// dtype self-detection — run ONCE in k_prep, result published to ws flag.
template<int T>
static __device__ __forceinline__ int detect_isf(const unsigned int* __restrict__ adjw,
                                                 int tid, int* sh_flag) {
    if (tid == 0) *sh_flag = 0;
    __syncthreads();
    int hit = 0;
    for (int k = tid; k < 1024; k += T)
        if ((adjw[k] & 0xFFFFu) == 0x3F80u) hit = 1;
    if (hit) *sh_flag = 1;
    __syncthreads();
    return (*sh_flag == 0) ? 1 : 0;
}

// ================= K1: detect + zero + x-stats + param copies ===============
// grid 192: bid<128 x-stats (128 rows each); bid>=128: zero + copies + flag.
__global__ __launch_bounds__(512) void k_prep(const void* __restrict__ adj,
        const void* __restrict__ x,
        const void* __restrict__ fc_g, const void* __restrict__ fc_b,
        const void* __restrict__ lin_W, const void* __restrict__ lin_b,
        const void* __restrict__ hid_g, const void* __restrict__ hid_b,
        const void* __restrict__ cls_W, const void* __restrict__ cls_b,
        const void* __restrict__ convs_b, float* ws) {
    __shared__ __align__(16) float XS[1024];
    __shared__ int sflag;
    int tid = threadIdx.x, bid = blockIdx.x;
    const int isf = detect_isf<512>((const unsigned int*)adj, tid, &sflag);
    if (bid < 128) {
        int f = tid & 127, part = tid >> 7;           // 4 parts x 32 rows
        int r0 = bid*128 + part*32;
        float s = 0.f, q = 0.f;
        for (int r = 0; r < 32; ++r) {
            float v = ldin(x, (size_t)(r0 + r)*FF + f, isf);
            s += v; q += v*v;
        }
        XS[part*128 + f] = s; XS[512 + part*128 + f] = q;
        __syncthreads();
        if (part == 0) {
            ws[OFF_XB + (size_t)bid*256 + f] =
                XS[f] + XS[128+f] + XS[256+f] + XS[384+f];
            ws[OFF_XB + (size_t)bid*256 + 128 + f] =
                XS[512+f] + XS[640+f] + XS[768+f] + XS[896+f];
        }
    } else {
        int gid = (bid - 128)*512 + tid;              // 0..32767
        if (gid == 0) ((int*)(ws + OFF_FLG))[0] = isf;
        for (size_t i = gid; i < ZERO_SZ; i += 32768) ws[OFF_G + i] = 0.f;
        float* prm = ws + OFF_PRM;
        if (gid < 192) {
            prm[gid]       = ldin(fc_g,  gid, isf);
            prm[192 + gid] = ldin(fc_b,  gid, isf);
            prm[384 + gid] = ldin(lin_b, gid, isf);
            prm[576 + gid] = ldin(hid_g, gid, isf);
            prm[768 + gid] = ldin(hid_b, gid, isf);
        }
        if (gid < 10)   prm[960 + gid]  = ldin(cls_b, gid, isf);
        if (gid < 1920) prm[976 + gid]  = ldin(cls_W, gid, isf);
        if (gid < 576)  prm[2896 + gid] = ldin(convs_b, gid, isf);
        unsigned short* wlt = (unsigned short*)(ws + OFF_WLT);
        for (int i = gid; i < HH*HH; i += 32768)
            wlt[i] = bf16bits(ldin(lin_W, i, isf));
    }
}

// ================= K2: fold feat W (once) ===================================
__global__ __launch_bounds__(128) void k_fold0(const void* __restrict__ W_feat,
        const void* __restrict__ gg, const void* __restrict__ bb, float* ws) {
    __shared__ float red[FF];
    int n = blockIdx.x, k = threadIdx.x;
    const int isf = rdflag(ws);
    float s = 0.f, q = 0.f;
    for (int b = 0; b < 128; ++b) {
        s += ws[OFF_XB + (size_t)b*256 + k];
        q += ws[OFF_XB + (size_t)b*256 + 128 + k];
    }
    float m   = s * (1.f/NROWS);
    float var = q * (1.f/NROWS) - m*m;
    float a   = ldin(gg, k, isf) * rsqrtf(var + EPSV);
    float c   = ldin(bb, k, isf) - m*a;
    float wv  = ldin(W_feat, (size_t)k*HH + n, isf);
    ((__hip_bfloat16*)(ws + OFF_WPF))[(size_t)n*FF + k] = __float2bfloat16(a*wv);
    red[k] = c*wv;
    __syncthreads();
    for (int s2 = FF/2; s2 > 0; s2 >>= 1) {
        if (k < s2) red[k] += red[k + s2];
        __syncthreads();
    }
    if (k == 0) ws[OFF_BF + n] = red[0];
}

// ================= K per-layer: fold conv W (once) ==========================
__global__ __launch_bounds__(192) void k_foldc(const void* __restrict__ convs_W,
        const void* __restrict__ gg, const void* __restrict__ bb,
        int layer, float* ws) {
    __shared__ float red[HH];
    int n = blockIdx.x, k = threadIdx.x;
    const int isf = rdflag(ws);
    const float* st = ws + OFF_SH + (size_t)layer*4096;
    float s = 0.f, q = 0.f;
    #pragma unroll
    for (int b = 0; b < 8; ++b) {
        s += st[b*512 + k];
        q += st[b*512 + 256 + k];
    }
    float m   = s * (1.f/NROWS);
    float var = q * (1.f/NROWS) - m*m;
    float a   = ldin(gg, (size_t)layer*HH + k, isf) * rsqrtf(var + EPSV);
    float c   = ldin(bb, (size_t)layer*HH + k, isf) - m*a;
    float wv  = ldin(convs_W, (size_t)layer*HH*HH + (size_t)k*HH + n, isf);
    ((__hip_bfloat16*)(ws + OFF_WPC))[(size_t)n*HH + k] = __float2bfloat16(a*wv);
    red[k] = c*wv;
    __syncthreads();
    if (k < 96) red[k] += red[k + 96];
    __syncthreads();
    for (int s2 = 48; s2 >= 3; s2 >>= 1) {
        if (k < s2) red[k] += red[k + s2];
        __syncthreads();
    }
    if (k == 0) ws[OFF_BC + n] = red[0] + red[1] + red[2];
}

// ================= K3: gemm0 (bid<512) + wave-ballot graph build ============
// gemm0: 32r x 192c tile, 8 waves (2r x 4c); B = WPF from L2.
// graph: bid>=512: 32 rows/block, one row per wave iter, ballot compaction
//        (no LDS, no barriers, no atomics).
__global__ __launch_bounds__(512, 4) void k_gg0(const void* __restrict__ adj,
        const void* __restrict__ x, float* ws) {
    __shared__ __align__(16) float SH2[384];
    int tid = threadIdx.x, bid = blockIdx.x;
    const int isf = rdflag(ws);
    if (bid < 512) {
        // ---------------- gemm0 ----------------
        for (int i = tid; i < 384; i += 512) SH2[i] = 0.f;
        __syncthreads();
        int lane = tid & 63, w = tid >> 6;
        int wr = w & 1, wc = w >> 1;
        int m = lane & 15, quad = lane >> 4;
        int batch = bid & 15, seg = bid >> 4;
        int row0 = batch*NN + seg*32;
        const __hip_bfloat16* BT = (const __hip_bfloat16*)(ws + OFF_WPF);
        float bv[3];
        #pragma unroll
        for (int tt = 0; tt < 3; ++tt) bv[tt] = ws[OFF_BF + wc*48 + tt*16 + m];
        f32x4 acc[3];
        #pragma unroll
        for (int tt = 0; tt < 3; ++tt) acc[tt] = f32x4{0.f,0.f,0.f,0.f};
        int rowA = row0 + wr*16 + m;
        #pragma unroll
        for (int kb = 0; kb < FF/32; ++kb) {
            short8 a;
            if (isf) {
                const float* Ar = (const float*)x + (size_t)rowA*FF + kb*32 + quad*8;
                f32x4 v0 = *(const f32x4*)Ar, v1 = *(const f32x4*)(Ar + 4);
                union { short8 s8; __hip_bfloat16 h[8]; } u;
                #pragma unroll
                for (int e = 0; e < 4; ++e) {
                    u.h[e]   = __float2bfloat16(v0[e]);
                    u.h[e+4] = __float2bfloat16(v1[e]);
                }
                a = u.s8;
            } else {
                a = *(const short8*)((const __hip_bfloat16*)x +
                                     (size_t)rowA*FF + kb*32 + quad*8);
            }
            #pragma unroll
            for (int tt = 0; tt < 3; ++tt) {
                short8 b = *(const short8*)(BT + (size_t)(wc*48 + tt*16 + m)*FF +
                                            kb*32 + quad*8);
                acc[tt] = __builtin_amdgcn_mfma_f32_16x16x32_bf16(a, b, acc[tt], 0, 0, 0);
            }
        }
        __hip_bfloat16* H0 = (__hip_bfloat16*)(ws + OFF_H0);
        #pragma unroll
        for (int tt = 0; tt < 3; ++tt) {
            int nl = wc*48 + tt*16 + m;
            float s = 0.f, sq = 0.f;
            #pragma unroll
            for (int r = 0; r < 4; ++r) {
                int row = row0 + wr*16 + quad*4 + r;
                float o = fmaxf(acc[tt][r] + bv[tt], 0.f);
                H0[(size_t)row*HH + nl] = __float2bfloat16(o);
                s += o; sq += o*o;
            }
            s  += __shfl_xor(s, 16, 64);  s  += __shfl_xor(s, 32, 64);
            sq += __shfl_xor(sq, 16, 64); sq += __shfl_xor(sq, 32, 64);
            if (quad == 0) {
                atomicAdd(&SH2[nl], s);
                atomicAdd(&SH2[192 + nl], sq);
            }
        }
        __syncthreads();
        float* st = ws + OFF_SH + (size_t)(bid & 7)*512;
        if (tid < 192) {
            atomicAdd(&st[tid], SH2[tid]);
            atomicAdd(&st[256 + tid], SH2[192 + tid]);
        }
    } else {
        // ---------------- graph build ----------------
        int gb = bid - 512;
        int wv = tid >> 6, lane = tid & 63;
        unsigned short* cols = (unsigned short*)(ws + OFF_COLS);
        unsigned long long lmask = (1ull << lane) - 1ull;
        #pragma unroll
        for (int rr = 0; rr < 4; ++rr) {
            int row = gb*32 + wv*4 + rr;
            int irow = row & (NN - 1);
            int base = 0;
            if (isf) {
                const unsigned int* ap = (const unsigned int*)adj + (size_t)row*NN;
                #pragma unroll
                for (int i = 0; i < 4; ++i) {
                    u32x4 v = *(const u32x4*)(ap + i*256 + lane*4);
                    #pragma unroll
                    for (int e = 0; e < 4; ++e) {
                        int j = i*256 + lane*4 + e;
                        bool hit = ((v[e] & 0x7FFFFFFFu) != 0u) || (j == irow);
                        unsigned long long mk = __ballot(hit);
                        int rk = __popcll(mk & lmask);
                        if (hit) {
                            int p = base + rk;
                            if (p < MAXC) cols[(size_t)row*MAXC + p] = (unsigned short)j;
                        }
                        base += __popcll(mk);
                    }
                }
            } else {
                const unsigned int* ap = (const unsigned int*)adj + (size_t)row*(NN/2);
                #pragma unroll
                for (int i = 0; i < 2; ++i) {
                    u32x4 v = *(const u32x4*)(ap + i*256 + lane*4);
                    #pragma unroll
                    for (int e = 0; e < 4; ++e) {
                        int wid = i*256 + lane*4 + e;
                        #pragma unroll
                        for (int h = 0; h < 2; ++h) {
                            unsigned int hv = (h == 0) ? (v[e] & 0xFFFFu) : (v[e] >> 16);
                            int j = 2*wid + h;
                            bool hit = ((hv & 0x7FFFu) != 0u) || (j == irow);
                            unsigned long long mk = __ballot(hit);
                            int rk = __popcll(mk & lmask);
                            if (hit) {
                                int p = base + rk;
                                if (p < MAXC) cols[(size_t)row*MAXC + p] = (unsigned short)j;
                            }
                            base += __popcll(mk);
                        }
                    }
                }
            }
            if (lane == 0) {
                ((int*)(ws + OFF_CNT))[row] = base > MAXC ? MAXC : base;
                ws[OFF_DIS + row] = rsqrtf((float)base);   // deg >= 1 (self loop)
            }
        }
    }
}

// ================= K per-layer: conv gemm (32r x 192c) ======================
__global__ __launch_bounds__(512, 4) void k_gemmc(float* __restrict__ ws) {
    __shared__ __align__(16) unsigned short ZT[32*HH];   // 12 KB
    int tid = threadIdx.x, bid = blockIdx.x;
    int lane = tid & 63, w = tid >> 6;
    int wr = w & 1, wc = w >> 1;
    int m = lane & 15, quad = lane >> 4;
    int batch = bid & 15, seg = bid >> 4;
    int row0 = batch*NN + seg*32;
    const __hip_bfloat16* A = (const __hip_bfloat16*)(ws + OFF_H0);
    const __hip_bfloat16* BT = (const __hip_bfloat16*)(ws + OFF_WPC);
    float bv[3];
    #pragma unroll
    for (int tt = 0; tt < 3; ++tt) bv[tt] = ws[OFF_BC + wc*48 + tt*16 + m];
    f32x4 acc[3];
    #pragma unroll
    for (int tt = 0; tt < 3; ++tt) acc[tt] = f32x4{0.f,0.f,0.f,0.f};
    int rowA = row0 + wr*16 + m;
    #pragma unroll
    for (int kb = 0; kb < HH/32; ++kb) {
        short8 a = *(const short8*)(A + (size_t)rowA*HH + kb*32 + quad*8);
        #pragma unroll
        for (int tt = 0; tt < 3; ++tt) {
            short8 b = *(const short8*)(BT + (size_t)(wc*48 + tt*16 + m)*HH +
                                        kb*32 + quad*8);
            acc[tt] = __builtin_amdgcn_mfma_f32_16x16x32_bf16(a, b, acc[tt], 0, 0, 0);
        }
    }
    const float* dis = ws + OFF_DIS;
    float sc[4];
    #pragma unroll
    for (int r = 0; r < 4; ++r) sc[r] = dis[row0 + wr*16 + quad*4 + r];
    #pragma unroll
    for (int tt = 0; tt < 3; ++tt) {
        int nl = wc*48 + tt*16 + m;
        #pragma unroll
        for (int r = 0; r < 4; ++r)
            ZT[(wr*16 + quad*4 + r)*HH + nl] = bf16bits((acc[tt][r] + bv[tt])*sc[r]);
    }
    __syncthreads();
    unsigned int* Zg = (unsigned int*)(ws + OFF_ZB) + (size_t)row0*96;
    const unsigned int* ZTu = (const unsigned int*)ZT;
    #pragma unroll
    for (int ii = 0; ii < 3; ++ii) {
        int i = tid + ii*512;          // 1536 u32x2 words total
        *(u32x2*)(&Zg[2*i]) = *(const u32x2*)(&ZTu[2*i]);
    }
}

// ================= K per-layer: spmm direct-from-L2 =========================
// grid 3072 = 16 batch x 6 slice x 32 rowgroup; block 256 = 32 rows x 8 lanes.
__global__ __launch_bounds__(256, 6) void k_spmm(int layer, float* __restrict__ ws) {
    __shared__ float SH[64];
    int tid = threadIdx.x, bid = blockIdx.x;
    for (int i = tid; i < 64; i += 256) SH[i] = 0.f;
    int batch = bid / 192, rem = bid - batch*192;
    int slice = rem >> 5, rg = rem & 31;
    int u = tid >> 3, d = tid & 7;
    int row = batch*NN + rg*32 + u;
    int c0 = slice*32;
    int base = slice*16 + d*2;
    const int c = ((const int*)(ws + OFF_CNT))[row];
    const unsigned short* cl = (const unsigned short*)(ws + OFF_COLS) + (size_t)row*MAXC;
    const unsigned int* Zb = (const unsigned int*)(ws + OFF_ZB) + (size_t)batch*NN*96;
    float bch[4];
    #pragma unroll
    for (int e = 0; e < 4; ++e)
        bch[e] = ws[OFF_PRM + 2896 + (size_t)layer*HH + c0 + d*4 + e];
    float a0=0.f, a1=0.f, a2=0.f, a3=0.f;
    int k = 0;
    for (; k + 8 <= c; k += 8) {
        u32x4 cw = *(const u32x4*)(cl + k);
        int j[8];
        j[0]=(int)(cw[0]&0xFFFFu); j[1]=(int)(cw[0]>>16);
        j[2]=(int)(cw[1]&0xFFFFu); j[3]=(int)(cw[1]>>16);
        j[4]=(int)(cw[2]&0xFFFFu); j[5]=(int)(cw[2]>>16);
        j[6]=(int)(cw[3]&0xFFFFu); j[7]=(int)(cw[3]>>16);
        u32x2 z[8];
        #pragma unroll
        for (int e = 0; e < 8; ++e)
            z[e] = *(const u32x2*)(&Zb[(size_t)j[e]*96 + base]);
        #pragma unroll
        for (int e = 0; e < 8; ++e) {
            a0 += blo(z[e][0]); a1 += bhi(z[e][0]);
            a2 += blo(z[e][1]); a3 += bhi(z[e][1]);
        }
    }
    for (; k < c; ++k) {
        u32x2 z = *(const u32x2*)(&Zb[(size_t)cl[k]*96 + base]);
        a0 += blo(z[0]); a1 += bhi(z[0]);
        a2 += blo(z[1]); a3 += bhi(z[1]);
    }
    float dd = ws[OFF_DIS + row];
    float o0 = fmaxf(dd*a0 + bch[0], 0.f);
    float o1 = fmaxf(dd*a1 + bch[1], 0.f);
    float o2 = fmaxf(dd*a2 + bch[2], 0.f);
    float o3 = fmaxf(dd*a3 + bch[3], 0.f);
    unsigned int* H0u = (unsigned int*)(ws + OFF_H0);
    u32x2 outw; outw[0] = packbf(o0,o1); outw[1] = packbf(o2,o3);
    *(u32x2*)(&H0u[(size_t)row*96 + base]) = outw;
    float s_acc[4] = {o0,o1,o2,o3};
    float q_acc[4] = {o0*o0,o1*o1,o2*o2,o3*o3};
    const int is_pool = (layer == 2);
    #pragma unroll
    for (int e = 0; e < 4; ++e) {
        #pragma unroll
        for (int mask = 8; mask < 64; mask <<= 1) {
            s_acc[e] += __shfl_xor(s_acc[e], mask, 64);
            if (!is_pool) q_acc[e] += __shfl_xor(q_acc[e], mask, 64);
        }
    }
    __syncthreads();
    if ((tid & 63) < 8) {
        #pragma unroll
        for (int e = 0; e < 4; ++e) {
            atomicAdd(&SH[d*4 + e], s_acc[e]);
            if (!is_pool) atomicAdd(&SH[32 + d*4 + e], q_acc[e]);
        }
    }
    __syncthreads();
    if (tid < 32) {
        if (is_pool) {
            atomicAdd(&ws[OFF_G + (size_t)batch*HH + c0 + tid], SH[tid]);
        } else {
            float* st = ws + OFF_SH + (size_t)(layer + 1)*4096 + (size_t)(bid & 7)*512;
            atomicAdd(&st[c0 + tid],       SH[tid]);
            atomicAdd(&st[256 + c0 + tid], SH[32 + tid]);
        }
    }
}

// ================= tail (params from ws; flag only for out dtype) ===========
__global__ __launch_bounds__(512) void k_tail(void* __restrict__ out,
                                              const float* __restrict__ ws) {
    __shared__ __align__(16) char SM_[62144];
    int tid = threadIdx.x;
    const int isf = rdflag(ws);
    const float* prm = ws + OFF_PRM;
    __hip_bfloat16* Wl = (__hip_bfloat16*)SM_;
    float* G1  = (float*)(SM_ + 36864);
    float* G2  = (float*)(SM_ + 49152);
    float* LG  = (float*)(SM_ + 61440);
    float* LSE = (float*)(SM_ + 62080);
    const float* g = ws + OFF_G;
    if (tid < HH) {
        float s = 0.f, sq = 0.f;
        for (int b = 0; b < BB; ++b) {
            float v = g[b*HH + tid]*(1.f/NN);
            s += v; sq += v*v;
        }
        float mean = s*(1.f/BB), var = sq*(1.f/BB) - mean*mean;
        float a = prm[tid] * rsqrtf(var + EPSV);
        float c = prm[192 + tid] - mean*a;
        for (int b = 0; b < BB; ++b) G1[b*HH + tid] = g[b*HH + tid]*(1.f/NN)*a + c;
    }
    int b = tid >> 5, grp = tid & 31, n0 = grp*6;
    float acc[6];
    #pragma unroll
    for (int e = 0; e < 6; ++e) acc[e] = prm[384 + n0 + e];
    const short8* Wsrc = (const short8*)(ws + OFF_WLT);
    for (int ch = 0; ch < 2; ++ch) {
        __syncthreads();
        for (int i = tid; i < 96*HH/8; i += 512)
            *(short8*)&Wl[8*i] = Wsrc[(size_t)ch*96*HH/8 + i];
        __syncthreads();
        for (int k = 0; k < 96; ++k) {
            float gv = G1[b*HH + ch*96 + k];
            const unsigned int* wp = (const unsigned int*)&Wl[k*HH + n0];
            unsigned int w0 = wp[0], w1 = wp[1], w2 = wp[2];
            acc[0] += gv*blo(w0); acc[1] += gv*bhi(w0);
            acc[2] += gv*blo(w1); acc[3] += gv*bhi(w1);
            acc[4] += gv*blo(w2); acc[5] += gv*bhi(w2);
        }
    }
    __syncthreads();
    #pragma unroll
    for (int e = 0; e < 6; ++e) G2[b*HH + n0 + e] = fmaxf(acc[e], 0.f);
    __syncthreads();
    if (tid < HH) {
        float s = 0.f, sq = 0.f;
        for (int bb = 0; bb < BB; ++bb) { float v = G2[bb*HH + tid]; s += v; sq += v*v; }
        float mean = s*(1.f/BB), var = sq*(1.f/BB) - mean*mean;
        float a = prm[576 + tid] * rsqrtf(var + EPSV);
        float c = prm[768 + tid] - mean*a;
        for (int bb = 0; bb < BB; ++bb) G2[bb*HH + tid] = G2[bb*HH + tid]*a + c;
    }
    __syncthreads();
    if (tid < BB*10) {
        int bb = tid/10, kk = tid%10;
        float a2 = prm[960 + kk];
        for (int h = 0; h < HH; ++h) a2 += G2[bb*HH + h]*prm[976 + h*10 + kk];
        LG[bb*10 + kk] = a2;
    }
    __syncthreads();
    if (tid < BB) {
        float mx = -1e30f;
        for (int k = 0; k < 10; ++k) mx = fmaxf(mx, LG[tid*10 + k]);
        float s = 0.f;
        for (int k = 0; k < 10; ++k) s += expf(LG[tid*10 + k] - mx);
        LSE[tid] = mx + logf(s);
    }
    __syncthreads();
    if (tid < BB*10) {
        int bb = tid/10;
        float v = LG[bb*10 + tid%10] - LSE[bb];
        if (isf) ((float*)out)[tid] = v;
        else     ((__hip_bfloat16*)out)[tid] = __float2bfloat16(v);
    }
}

extern "C" void kernel_launch(void* const* d_in, const int* in_sizes, int n_in,
                              void* d_out, int out_size, void* d_ws, size_t ws_size,
                              hipStream_t stream) {
    const void* x       = d_in[0];
    const void* adj     = d_in[1];
    const void* bnf_g   = d_in[2];
    const void* bnf_b   = d_in[3];
    const void* W_feat  = d_in[4];
    const void* bnc_g   = d_in[5];
    const void* bnc_b   = d_in[6];
    const void* convs_W = d_in[7];
    const void* convs_b = d_in[8];
    const void* fc_g    = d_in[9];
    const void* fc_b    = d_in[10];
    const void* lin_W   = d_in[11];
    const void* lin_b   = d_in[12];
    const void* hid_g   = d_in[13];
    const void* hid_b   = d_in[14];
    const void* cls_W   = d_in[15];
    const void* cls_b   = d_in[16];
    float* ws = (float*)d_ws;

    k_prep<<<192, 512, 0, stream>>>(adj, x, fc_g, fc_b, lin_W, lin_b,
                                    hid_g, hid_b, cls_W, cls_b, convs_b, ws);
    k_fold0<<<HH, FF, 0, stream>>>(W_feat, bnf_g, bnf_b, ws);
    k_gg0<<<1024, 512, 0, stream>>>(adj, x, ws);
    for (int l = 0; l < 3; ++l) {
        k_foldc<<<HH, HH, 0, stream>>>(convs_W, bnc_g, bnc_b, l, ws);
        k_gemmc<<<512, 512, 0, stream>>>(ws);
        k_spmm<<<3072, 256, 0, stream>>>(l, ws);
    }
    k_tail<<<1, 512, 0, stream>>>(d_out, ws);
}

// Round 8
// 293.732 us; speedup vs baseline: 1.2852x; 1.0234x over previous
//
#include <hip/hip_runtime.h>
#include <hip/hip_bf16.h>

#define BB 16
#define NN 1024
#define FF 128
#define HH 192
#define NROWS (BB*NN)
#define MAXC 128
#define EPSV 1e-5f

// ---------------- workspace layout (float units) ----------------
constexpr size_t OFF_H0  = 0;                                 // [NROWS*HH] bf16
constexpr size_t OFF_ZB  = OFF_H0 + (size_t)NROWS*HH/2;       // [NROWS*HH] bf16
constexpr size_t OFF_DIS = OFF_ZB + (size_t)NROWS*HH/2;       // [NROWS] f32
constexpr size_t OFF_G   = OFF_DIS + NROWS;                   // [BB*HH] pool sums
constexpr size_t OFF_SH  = OFF_G + BB*HH;                     // 3 stages x 8 buckets x 512
constexpr size_t SH_SIZE = 3*8*512;
constexpr size_t ZERO_SZ = BB*HH + SH_SIZE;                   // zeroed in k_prep
constexpr size_t OFF_FLG = OFF_SH + SH_SIZE;                  // [16] isf flag
constexpr size_t OFF_PRM = OFF_FLG + 16;                      // f32 params [3584]
// prm: 0 fc_g,192 fc_b,384 lin_b,576 hid_g,768 hid_b,960 cls_b(10),
//      976 cls_W(1920), 2896 convs_b(576)
constexpr size_t OFF_WLT = OFF_PRM + 3584;                    // lin_W bf16 [HH*HH]
constexpr size_t OFF_XB  = OFF_WLT + (size_t)HH*HH/2;         // x-stat buckets [128][256]
constexpr size_t OFF_WPF = OFF_XB + 128*256;                  // RAW W_feat^T bf16 [192][128]
constexpr size_t OFF_WPC = OFF_WPF + (size_t)HH*FF/2;         // RAW convs_W^T bf16 [3][192][192]
constexpr size_t OFF_CNT = OFF_WPC + 3*(size_t)HH*HH/2;       // [NROWS] int32
constexpr size_t OFF_COLS= OFF_CNT + NROWS;                   // [NROWS*MAXC] u16

typedef __attribute__((ext_vector_type(8))) short short8;
typedef __attribute__((ext_vector_type(4))) float f32x4;
typedef __attribute__((ext_vector_type(4))) unsigned int u32x4;
typedef __attribute__((ext_vector_type(2))) unsigned int u32x2;

static __device__ __forceinline__ float ldin(const void* p, size_t i, int isf) {
    return isf ? ((const float*)p)[i]
               : __bfloat162float(((const __hip_bfloat16*)p)[i]);
}
static __device__ __forceinline__ float blo(unsigned int u) {
    union { unsigned int x; float f; } v; v.x = u << 16; return v.f;
}
static __device__ __forceinline__ float bhi(unsigned int u) {
    union { unsigned int x; float f; } v; v.x = u & 0xFFFF0000u; return v.f;
}
static __device__ __forceinline__ unsigned int packbf(float a, float b) {
    union { unsigned int u; __hip_bfloat16 h[2]; } p;
    p.h[0] = __float2bfloat16(a); p.h[1] = __float2bfloat16(b);
    return p.u;
}
static __device__ __forceinline__ unsigned short bf16bits(float a) {
    union { unsigned short u; __hip_bfloat16 h; } p;
    p.h = __float2bfloat16(a); return p.u;
}
static __device__ __forceinline__ int rdflag(const float* ws) {
    return ((const int*)(ws + OFF_FLG))[0];
}

// dtype self-detection — run ONLY inside k_prep; published to ws flag.
template<int T>
static __device__ __forceinline__ int detect_isf(const unsigned int* __restrict__ adjw,
                                                 int tid, int* sh_flag) {
    if (tid == 0) *sh_flag = 0;
    __syncthreads();
    int hit = 0;
    for (int k = tid; k < 1024; k += T)
        if ((adjw[k] & 0xFFFFu) == 0x3F80u) hit = 1;
    if (hit) *sh_flag = 1;
    __syncthreads();
    return (*sh_flag == 0) ? 1 : 0;
}

// ================= K1: detect + zero + x-stats + copies + graph =============
// grid 704: bid<128 x-stats; 128<=bid<192 zero/copies/W-conversions;
//           bid>=192: ballot graph build (512 blocks x 32 rows).
__global__ __launch_bounds__(512) void k_prep(const void* __restrict__ adj,
        const void* __restrict__ x,
        const void* __restrict__ W_feat, const void* __restrict__ convs_W,
        const void* __restrict__ fc_g, const void* __restrict__ fc_b,
        const void* __restrict__ lin_W, const void* __restrict__ lin_b,
        const void* __restrict__ hid_g, const void* __restrict__ hid_b,
        const void* __restrict__ cls_W, const void* __restrict__ cls_b,
        const void* __restrict__ convs_b, float* ws) {
    __shared__ __align__(16) float XS[1024];
    __shared__ int sflag;
    int tid = threadIdx.x, bid = blockIdx.x;
    const int isf = detect_isf<512>((const unsigned int*)adj, tid, &sflag);
    if (bid < 128) {
        int f = tid & 127, part = tid >> 7;           // 4 parts x 32 rows
        int r0 = bid*128 + part*32;
        float s = 0.f, q = 0.f;
        for (int r = 0; r < 32; ++r) {
            float v = ldin(x, (size_t)(r0 + r)*FF + f, isf);
            s += v; q += v*v;
        }
        XS[part*128 + f] = s; XS[512 + part*128 + f] = q;
        __syncthreads();
        if (part == 0) {
            ws[OFF_XB + (size_t)bid*256 + f] =
                XS[f] + XS[128+f] + XS[256+f] + XS[384+f];
            ws[OFF_XB + (size_t)bid*256 + 128 + f] =
                XS[512+f] + XS[640+f] + XS[768+f] + XS[896+f];
        }
    } else if (bid < 192) {
        int gid = (bid - 128)*512 + tid;              // 0..32767
        if (gid == 0) ((int*)(ws + OFF_FLG))[0] = isf;
        for (size_t i = gid; i < ZERO_SZ; i += 32768) ws[OFF_G + i] = 0.f;
        float* prm = ws + OFF_PRM;
        if (gid < 192) {
            prm[gid]       = ldin(fc_g,  gid, isf);
            prm[192 + gid] = ldin(fc_b,  gid, isf);
            prm[384 + gid] = ldin(lin_b, gid, isf);
            prm[576 + gid] = ldin(hid_g, gid, isf);
            prm[768 + gid] = ldin(hid_b, gid, isf);
        }
        if (gid < 10)   prm[960 + gid]  = ldin(cls_b, gid, isf);
        if (gid < 1920) prm[976 + gid]  = ldin(cls_W, gid, isf);
        if (gid < 576)  prm[2896 + gid] = ldin(convs_b, gid, isf);
        unsigned short* wlt = (unsigned short*)(ws + OFF_WLT);
        for (int i = gid; i < HH*HH; i += 32768)
            wlt[i] = bf16bits(ldin(lin_W, i, isf));
        // raw W^T conversions (coalesced read, scattered 2B write -> L2)
        unsigned short* wpf = (unsigned short*)(ws + OFF_WPF);
        if (gid < FF*HH) {                            // 24576
            int k = gid / HH, n = gid - k*HH;
            wpf[(size_t)n*FF + k] = bf16bits(ldin(W_feat, (size_t)k*HH + n, isf));
        }
        unsigned short* wpc = (unsigned short*)(ws + OFF_WPC);
        for (int i = gid; i < 3*HH*HH; i += 32768) {  // 110592
            int l = i / (HH*HH), r2 = i - l*HH*HH;
            int k = r2 / HH, n = r2 - k*HH;
            wpc[(size_t)l*HH*HH + (size_t)n*HH + k] =
                bf16bits(ldin(convs_W, (size_t)l*HH*HH + (size_t)k*HH + n, isf));
        }
    } else {
        // ---------------- graph build (ballot compaction) ----------------
        int gb = bid - 192;
        int wv = tid >> 6, lane = tid & 63;
        unsigned short* cols = (unsigned short*)(ws + OFF_COLS);
        unsigned long long lmask = (1ull << lane) - 1ull;
        #pragma unroll
        for (int rr = 0; rr < 4; ++rr) {
            int row = gb*32 + wv*4 + rr;
            int irow = row & (NN - 1);
            int base = 0;
            if (isf) {
                const unsigned int* ap = (const unsigned int*)adj + (size_t)row*NN;
                #pragma unroll
                for (int i = 0; i < 4; ++i) {
                    u32x4 v = *(const u32x4*)(ap + i*256 + lane*4);
                    #pragma unroll
                    for (int e = 0; e < 4; ++e) {
                        int j = i*256 + lane*4 + e;
                        bool hit = ((v[e] & 0x7FFFFFFFu) != 0u) || (j == irow);
                        unsigned long long mk = __ballot(hit);
                        int rk = __popcll(mk & lmask);
                        if (hit) {
                            int p = base + rk;
                            if (p < MAXC) cols[(size_t)row*MAXC + p] = (unsigned short)j;
                        }
                        base += __popcll(mk);
                    }
                }
            } else {
                const unsigned int* ap = (const unsigned int*)adj + (size_t)row*(NN/2);
                #pragma unroll
                for (int i = 0; i < 2; ++i) {
                    u32x4 v = *(const u32x4*)(ap + i*256 + lane*4);
                    #pragma unroll
                    for (int e = 0; e < 4; ++e) {
                        int wid = i*256 + lane*4 + e;
                        #pragma unroll
                        for (int h = 0; h < 2; ++h) {
                            unsigned int hv = (h == 0) ? (v[e] & 0xFFFFu) : (v[e] >> 16);
                            int j = 2*wid + h;
                            bool hit = ((hv & 0x7FFFu) != 0u) || (j == irow);
                            unsigned long long mk = __ballot(hit);
                            int rk = __popcll(mk & lmask);
                            if (hit) {
                                int p = base + rk;
                                if (p < MAXC) cols[(size_t)row*MAXC + p] = (unsigned short)j;
                            }
                            base += __popcll(mk);
                        }
                    }
                }
            }
            if (lane == 0) {
                ((int*)(ws + OFF_CNT))[row] = base > MAXC ? MAXC : base;
                ws[OFF_DIS + row] = rsqrtf((float)base);   // deg >= 1 (self loop)
            }
        }
    }
}

// ================= K2: gemm0 with in-register A-side BN fold ================
// A' = a_k*x + c_k (regs) -> A'@W already includes the c-term; NO extra bias.
__global__ __launch_bounds__(512, 4) void k_gemm0(const void* __restrict__ x,
        const void* __restrict__ gg, const void* __restrict__ bb,
        float* __restrict__ ws) {
    __shared__ __align__(16) float AF[FF], CF[FF], SH2[384];
    int tid = threadIdx.x, bid = blockIdx.x;
    const int isf = rdflag(ws);
    if (tid < FF) {
        float s = 0.f, q = 0.f;
        for (int b = 0; b < 128; ++b) {
            s += ws[OFF_XB + (size_t)b*256 + tid];
            q += ws[OFF_XB + (size_t)b*256 + 128 + tid];
        }
        float mean = s*(1.f/NROWS), var = q*(1.f/NROWS) - mean*mean;
        float a = ldin(gg, tid, isf) * rsqrtf(var + EPSV);
        AF[tid] = a;
        CF[tid] = ldin(bb, tid, isf) - mean*a;
    }
    for (int i = tid; i < 384; i += 512) SH2[i] = 0.f;
    __syncthreads();
    const __hip_bfloat16* BT = (const __hip_bfloat16*)(ws + OFF_WPF);
    int lane = tid & 63, w8 = tid >> 6;
    int wr = w8 & 1, wc = w8 >> 1;
    int m = lane & 15, quad = lane >> 4;
    int batch = bid & 15, seg = bid >> 4;
    int row0 = batch*NN + seg*32;
    int rowA = row0 + wr*16 + m;
    f32x4 acc[3];
    #pragma unroll
    for (int tt = 0; tt < 3; ++tt) acc[tt] = f32x4{0.f,0.f,0.f,0.f};
    #pragma unroll
    for (int kb = 0; kb < FF/32; ++kb) {
        int k0 = kb*32 + quad*8;
        float xv[8];
        if (isf) {
            const float* Ar = (const float*)x + (size_t)rowA*FF + k0;
            f32x4 v0 = *(const f32x4*)Ar, v1 = *(const f32x4*)(Ar + 4);
            #pragma unroll
            for (int e = 0; e < 4; ++e) { xv[e] = v0[e]; xv[4+e] = v1[e]; }
        } else {
            union { short8 s8; __hip_bfloat16 h[8]; } u;
            u.s8 = *(const short8*)((const __hip_bfloat16*)x + (size_t)rowA*FF + k0);
            #pragma unroll
            for (int e = 0; e < 8; ++e) xv[e] = __bfloat162float(u.h[e]);
        }
        union { short8 s8; __hip_bfloat16 h[8]; } ua;
        #pragma unroll
        for (int e = 0; e < 8; ++e)
            ua.h[e] = __float2bfloat16(AF[k0+e]*xv[e] + CF[k0+e]);
        short8 a = ua.s8;
        #pragma unroll
        for (int tt = 0; tt < 3; ++tt) {
            short8 b = *(const short8*)(BT + (size_t)(wc*48 + tt*16 + m)*FF + k0);
            acc[tt] = __builtin_amdgcn_mfma_f32_16x16x32_bf16(a, b, acc[tt], 0, 0, 0);
        }
    }
    __hip_bfloat16* H0 = (__hip_bfloat16*)(ws + OFF_H0);
    #pragma unroll
    for (int tt = 0; tt < 3; ++tt) {
        int nl = wc*48 + tt*16 + m;
        float s = 0.f, sq = 0.f;
        #pragma unroll
        for (int r = 0; r < 4; ++r) {
            int row = row0 + wr*16 + quad*4 + r;
            float o = fmaxf(acc[tt][r], 0.f);         // c-term is inside A'@W
            H0[(size_t)row*HH + nl] = __float2bfloat16(o);
            s += o; sq += o*o;
        }
        s  += __shfl_xor(s, 16, 64);  s  += __shfl_xor(s, 32, 64);
        sq += __shfl_xor(sq, 16, 64); sq += __shfl_xor(sq, 32, 64);
        if (quad == 0) {
            atomicAdd(&SH2[nl], s);
            atomicAdd(&SH2[192 + nl], sq);
        }
    }
    __syncthreads();
    float* st = ws + OFF_SH + (size_t)(bid & 7)*512;
    if (tid < 192) {
        atomicAdd(&st[tid], SH2[tid]);
        atomicAdd(&st[256 + tid], SH2[192 + tid]);
    }
}

// ================= K per-layer: conv gemm with A-side BN fold ===============
__global__ __launch_bounds__(512, 4) void k_gemmc(const void* __restrict__ gg,
        const void* __restrict__ bb, int layer, float* __restrict__ ws) {
    __shared__ __align__(16) float AF[HH], CF[HH];
    __shared__ __align__(16) unsigned short ZT[32*HH];   // 12 KB
    int tid = threadIdx.x, bid = blockIdx.x;
    const int isf = rdflag(ws);
    if (tid < HH) {
        const float* st = ws + OFF_SH + (size_t)layer*4096;
        float s = 0.f, q = 0.f;
        #pragma unroll
        for (int b = 0; b < 8; ++b) {
            s += st[b*512 + tid];
            q += st[b*512 + 256 + tid];
        }
        float mean = s*(1.f/NROWS), var = q*(1.f/NROWS) - mean*mean;
        float a = ldin(gg, (size_t)layer*HH + tid, isf) * rsqrtf(var + EPSV);
        AF[tid] = a;
        CF[tid] = ldin(bb, (size_t)layer*HH + tid, isf) - mean*a;
    }
    __syncthreads();
    const __hip_bfloat16* BT = (const __hip_bfloat16*)(ws + OFF_WPC) +
                               (size_t)layer*HH*HH;
    int lane = tid & 63, w8 = tid >> 6;
    int wr = w8 & 1, wc = w8 >> 1;
    int m = lane & 15, quad = lane >> 4;
    int batch = bid & 15, seg = bid >> 4;
    int row0 = batch*NN + seg*32;
    int rowA = row0 + wr*16 + m;
    const __hip_bfloat16* A = (const __hip_bfloat16*)(ws + OFF_H0);
    f32x4 acc[3];
    #pragma unroll
    for (int tt = 0; tt < 3; ++tt) acc[tt] = f32x4{0.f,0.f,0.f,0.f};
    #pragma unroll
    for (int kb = 0; kb < HH/32; ++kb) {
        int k0 = kb*32 + quad*8;
        union { short8 s8; __hip_bfloat16 h[8]; } u;
        u.s8 = *(const short8*)(A + (size_t)rowA*HH + k0);
        union { short8 s8; __hip_bfloat16 h[8]; } ua;
        #pragma unroll
        for (int e = 0; e < 8; ++e)
            ua.h[e] = __float2bfloat16(AF[k0+e]*__bfloat162float(u.h[e]) + CF[k0+e]);
        short8 a = ua.s8;
        #pragma unroll
        for (int tt = 0; tt < 3; ++tt) {
            short8 b = *(const short8*)(BT + (size_t)(wc*48 + tt*16 + m)*HH + k0);
            acc[tt] = __builtin_amdgcn_mfma_f32_16x16x32_bf16(a, b, acc[tt], 0, 0, 0);
        }
    }
    const float* dis = ws + OFF_DIS;
    float sc[4];
    #pragma unroll
    for (int r = 0; r < 4; ++r) sc[r] = dis[row0 + wr*16 + quad*4 + r];
    #pragma unroll
    for (int tt = 0; tt < 3; ++tt) {
        int nl = wc*48 + tt*16 + m;
        #pragma unroll
        for (int r = 0; r < 4; ++r)
            ZT[(wr*16 + quad*4 + r)*HH + nl] = bf16bits(acc[tt][r]*sc[r]);
    }
    __syncthreads();
    unsigned int* Zg = (unsigned int*)(ws + OFF_ZB) + (size_t)row0*96;
    const unsigned int* ZTu = (const unsigned int*)ZT;
    #pragma unroll
    for (int ii = 0; ii < 3; ++ii) {
        int i = tid + ii*512;
        *(u32x2*)(&Zg[2*i]) = *(const u32x2*)(&ZTu[2*i]);
    }
}

// ================= K per-layer: spmm direct-from-L2 =========================
__global__ __launch_bounds__(256, 6) void k_spmm(int layer, float* __restrict__ ws) {
    __shared__ float SH[64];
    int tid = threadIdx.x, bid = blockIdx.x;
    for (int i = tid; i < 64; i += 256) SH[i] = 0.f;
    int batch = bid / 192, rem = bid - batch*192;
    int slice = rem >> 5, rg = rem & 31;
    int u = tid >> 3, d = tid & 7;
    int row = batch*NN + rg*32 + u;
    int c0 = slice*32;
    int base = slice*16 + d*2;
    const int c = ((const int*)(ws + OFF_CNT))[row];
    const unsigned short* cl = (const unsigned short*)(ws + OFF_COLS) + (size_t)row*MAXC;
    const unsigned int* Zb = (const unsigned int*)(ws + OFF_ZB) + (size_t)batch*NN*96;
    float bch[4];
    #pragma unroll
    for (int e = 0; e < 4; ++e)
        bch[e] = ws[OFF_PRM + 2896 + (size_t)layer*HH + c0 + d*4 + e];
    float a0=0.f, a1=0.f, a2=0.f, a3=0.f;
    int k = 0;
    for (; k + 8 <= c; k += 8) {
        u32x4 cw = *(const u32x4*)(cl + k);
        int j[8];
        j[0]=(int)(cw[0]&0xFFFFu); j[1]=(int)(cw[0]>>16);
        j[2]=(int)(cw[1]&0xFFFFu); j[3]=(int)(cw[1]>>16);
        j[4]=(int)(cw[2]&0xFFFFu); j[5]=(int)(cw[2]>>16);
        j[6]=(int)(cw[3]&0xFFFFu); j[7]=(int)(cw[3]>>16);
        u32x2 z[8];
        #pragma unroll
        for (int e = 0; e < 8; ++e)
            z[e] = *(const u32x2*)(&Zb[(size_t)j[e]*96 + base]);
        #pragma unroll
        for (int e = 0; e < 8; ++e) {
            a0 += blo(z[e][0]); a1 += bhi(z[e][0]);
            a2 += blo(z[e][1]); a3 += bhi(z[e][1]);
        }
    }
    for (; k < c; ++k) {
        u32x2 z = *(const u32x2*)(&Zb[(size_t)cl[k]*96 + base]);
        a0 += blo(z[0]); a1 += bhi(z[0]);
        a2 += blo(z[1]); a3 += bhi(z[1]);
    }
    float dd = ws[OFF_DIS + row];
    float o0 = fmaxf(dd*a0 + bch[0], 0.f);
    float o1 = fmaxf(dd*a1 + bch[1], 0.f);
    float o2 = fmaxf(dd*a2 + bch[2], 0.f);
    float o3 = fmaxf(dd*a3 + bch[3], 0.f);
    unsigned int* H0u = (unsigned int*)(ws + OFF_H0);
    u32x2 outw; outw[0] = packbf(o0,o1); outw[1] = packbf(o2,o3);
    *(u32x2*)(&H0u[(size_t)row*96 + base]) = outw;
    float s_acc[4] = {o0,o1,o2,o3};
    float q_acc[4] = {o0*o0,o1*o1,o2*o2,o3*o3};
    const int is_pool = (layer == 2);
    #pragma unroll
    for (int e = 0; e < 4; ++e) {
        #pragma unroll
        for (int mask = 8; mask < 64; mask <<= 1) {
            s_acc[e] += __shfl_xor(s_acc[e], mask, 64);
            if (!is_pool) q_acc[e] += __shfl_xor(q_acc[e], mask, 64);
        }
    }
    __syncthreads();
    if ((tid & 63) < 8) {
        #pragma unroll
        for (int e = 0; e < 4; ++e) {
            atomicAdd(&SH[d*4 + e], s_acc[e]);
            if (!is_pool) atomicAdd(&SH[32 + d*4 + e], q_acc[e]);
        }
    }
    __syncthreads();
    if (tid < 32) {
        if (is_pool) {
            atomicAdd(&ws[OFF_G + (size_t)batch*HH + c0 + tid], SH[tid]);
        } else {
            float* st = ws + OFF_SH + (size_t)(layer + 1)*4096 + (size_t)(bid & 7)*512;
            atomicAdd(&st[c0 + tid],       SH[tid]);
            atomicAdd(&st[256 + c0 + tid], SH[32 + tid]);
        }
    }
}

// ================= tail =====================================================
__global__ __launch_bounds__(512) void k_tail(void* __restrict__ out,
                                              const float* __restrict__ ws) {
    __shared__ __align__(16) char SM_[62144];
    int tid = threadIdx.x;
    const int isf = rdflag(ws);
    const float* prm = ws + OFF_PRM;
    __hip_bfloat16* Wl = (__hip_bfloat16*)SM_;
    float* G1  = (float*)(SM_ + 36864);
    float* G2  = (float*)(SM_ + 49152);
    float* LG  = (float*)(SM_ + 61440);
    float* LSE = (float*)(SM_ + 62080);
    const float* g = ws + OFF_G;
    if (tid < HH) {
        float s = 0.f, sq = 0.f;
        for (int b = 0; b < BB; ++b) {
            float v = g[b*HH + tid]*(1.f/NN);
            s += v; sq += v*v;
        }
        float mean = s*(1.f/BB), var = sq*(1.f/BB) - mean*mean;
        float a = prm[tid] * rsqrtf(var + EPSV);
        float c = prm[192 + tid] - mean*a;
        for (int b = 0; b < BB; ++b) G1[b*HH + tid] = g[b*HH + tid]*(1.f/NN)*a + c;
    }
    int b = tid >> 5, grp = tid & 31, n0 = grp*6;
    float acc[6];
    #pragma unroll
    for (int e = 0; e < 6; ++e) acc[e] = prm[384 + n0 + e];
    const short8* Wsrc = (const short8*)(ws + OFF_WLT);
    for (int ch = 0; ch < 2; ++ch) {
        __syncthreads();
        for (int i = tid; i < 96*HH/8; i += 512)
            *(short8*)&Wl[8*i] = Wsrc[(size_t)ch*96*HH/8 + i];
        __syncthreads();
        for (int k = 0; k < 96; ++k) {
            float gv = G1[b*HH + ch*96 + k];
            const unsigned int* wp = (const unsigned int*)&Wl[k*HH + n0];
            unsigned int w0 = wp[0], w1 = wp[1], w2 = wp[2];
            acc[0] += gv*blo(w0); acc[1] += gv*bhi(w0);
            acc[2] += gv*blo(w1); acc[3] += gv*bhi(w1);
            acc[4] += gv*blo(w2); acc[5] += gv*bhi(w2);
        }
    }
    __syncthreads();
    #pragma unroll
    for (int e = 0; e < 6; ++e) G2[b*HH + n0 + e] = fmaxf(acc[e], 0.f);
    __syncthreads();
    if (tid < HH) {
        float s = 0.f, sq = 0.f;
        for (int bb = 0; bb < BB; ++bb) { float v = G2[bb*HH + tid]; s += v; sq += v*v; }
        float mean = s*(1.f/BB), var = sq*(1.f/BB) - mean*mean;
        float a = prm[576 + tid] * rsqrtf(var + EPSV);
        float c = prm[768 + tid] - mean*a;
        for (int bb = 0; bb < BB; ++bb) G2[bb*HH + tid] = G2[bb*HH + tid]*a + c;
    }
    __syncthreads();
    if (tid < BB*10) {
        int bb = tid/10, kk = tid%10;
        float a2 = prm[960 + kk];
        for (int h = 0; h < HH; ++h) a2 += G2[bb*HH + h]*prm[976 + h*10 + kk];
        LG[bb*10 + kk] = a2;
    }
    __syncthreads();
    if (tid < BB) {
        float mx = -1e30f;
        for (int k = 0; k < 10; ++k) mx = fmaxf(mx, LG[tid*10 + k]);
        float s = 0.f;
        for (int k = 0; k < 10; ++k) s += expf(LG[tid*10 + k] - mx);
        LSE[tid] = mx + logf(s);
    }
    __syncthreads();
    if (tid < BB*10) {
        int bb = tid/10;
        float v = LG[bb*10 + tid%10] - LSE[bb];
        if (isf) ((float*)out)[tid] = v;
        else     ((__hip_bfloat16*)out)[tid] = __float2bfloat16(v);
    }
}

extern "C" void kernel_launch(void* const* d_in, const int* in_sizes, int n_in,
                              void* d_out, int out_size, void* d_ws, size_t ws_size,
                              hipStream_t stream) {
    const void* x       = d_in[0];
    const void* adj     = d_in[1];
    const void* bnf_g   = d_in[2];
    const void* bnf_b   = d_in[3];
    const void* W_feat  = d_in[4];
    const void* bnc_g   = d_in[5];
    const void* bnc_b   = d_in[6];
    const void* convs_W = d_in[7];
    const void* convs_b = d_in[8];
    const void* fc_g    = d_in[9];
    const void* fc_b    = d_in[10];
    const void* lin_W   = d_in[11];
    const void* lin_b   = d_in[12];
    const void* hid_g   = d_in[13];
    const void* hid_b   = d_in[14];
    const void* cls_W   = d_in[15];
    const void* cls_b   = d_in[16];
    float* ws = (float*)d_ws;

    k_prep<<<704, 512, 0, stream>>>(adj, x, W_feat, convs_W, fc_g, fc_b,
                                    lin_W, lin_b, hid_g, hid_b, cls_W, cls_b,
                                    convs_b, ws);
    k_gemm0<<<512, 512, 0, stream>>>(x, bnf_g, bnf_b, ws);
    for (int l = 0; l < 3; ++l) {
        k_gemmc<<<512, 512, 0, stream>>>(bnc_g, bnc_b, l, ws);
        k_spmm<<<3072, 256, 0, stream>>>(l, ws);
    }
    k_tail<<<1, 512, 0, stream>>>(d_out, ws);
}